// Round 7
// baseline (374.768 us; speedup 1.0000x reference)
//
#include <hip/hip_runtime.h>
#include <hip/hip_bf16.h>

namespace {
constexpr int kL = 720, kF = 128;
constexpr int kWin = 15;
constexpr float kEps = 1e-6f;
constexpr float kMaxN = 1.0f - 1e-5f;
constexpr int kT0off = 360;   // (30-15)*24: only last 15 segments matter
constexpr int ZTR = 132;      // zt row stride (floats), +4 pad (fused fallback)
constexpr int AROW = 104;     // A lds row stride bf16 (fused fallback)
constexpr int XR = 129;       // k1a2 fp32 X row stride (128 + 1: bank = (k+f)%32, conflict-free frag reads)
// ws offsets
constexpr size_t kOffT0   = 0;                    // 16 MiB bf16 t0
constexpr size_t kOffW1   = 16777216;             // 128 KiB bf16 W1 [n][k]
constexpr size_t kOffW2   = kOffW1 + 131072;      // 32 KiB bf16 W2 [p][k]
constexpr size_t kOffBt   = kOffW2 + 32768;       // 72 KiB: BtH/BtM/BtL [128][96] bf16
constexpr size_t kOffBsum = kOffBt + 73728;       // 512 B fp32
constexpr size_t kOffZ2   = 17018880;             // 1 MiB fp32 z2 [16384][16]
constexpr size_t kOffZ    = 18874368;             // 126 MiB fp32 z [16384][15][128]
constexpr size_t kWsNew   = kOffZ + 125829120;    // 144,703,488: split-K1 path (verified present in R5)
}

typedef float f32x4 __attribute__((ext_vector_type(4)));
typedef short s16x8 __attribute__((ext_vector_type(8)));

__device__ __forceinline__ float rcp_f(float x) { return __builtin_amdgcn_rcpf(x); }
__device__ __forceinline__ float sqrt_f(float x) { return __builtin_amdgcn_sqrtf(x); }
__device__ __forceinline__ float tanh_f(float x) {          // x >= 0
  float t = __builtin_amdgcn_exp2f(x * -2.8853900817779268f);
  return (1.0f - t) * rcp_f(1.0f + t);
}
__device__ __forceinline__ float artanh_f(float n) {        // n >= 0
  float nc = fminf(n, 1.0f - 1e-7f);
  return 0.34657359027997264f * __builtin_amdgcn_logf((1.0f + nc) * rcp_f(1.0f - nc));
}

// DPP butterfly add helpers (VALU-latency cross-lane, no LDS pipe).
template<int CTRL>
__device__ __forceinline__ float dpp_add(float v) {
  int mv = __builtin_amdgcn_update_dpp(0, __float_as_int(v), CTRL, 0xF, 0xF, false);
  return v + __int_as_float(mv);
}
__device__ __forceinline__ float sum16(float v) {
  v = dpp_add<0xB1>(v);
  v = dpp_add<0x4E>(v);
  v = dpp_add<0x141>(v);
  v = dpp_add<0x128>(v);
  return v;
}
__device__ __forceinline__ float sum64(float v) {
  v = sum16(v);
  v += __shfl_xor(v, 16);
  v += __shfl_xor(v, 32);
  return v;
}
__device__ __forceinline__ float rlane(float v, int i) {
  return __int_as_float(__builtin_amdgcn_readlane(__float_as_int(v), i));
}
// RNE bf16: returns 16-bit pattern, and the rounded value as f32 via fval.
__device__ __forceinline__ unsigned short rne_bf16(float f, float& fval) {
  unsigned u = __float_as_uint(f);
  unsigned r = (u + 0x7FFFu + ((u >> 16) & 1u)) & 0xFFFF0000u;
  fval = __uint_as_float(r);
  return (unsigned short)(r >> 16);
}

// ---------------- prep: weight repack (bf16 W1/W2 + 3-level split Bt + bsum) ----------------
extern "C" __global__ __launch_bounds__(256)
void mwhf_prep(const float* __restrict__ W1, const float* __restrict__ W2,
               const float* __restrict__ W_t, const float* __restrict__ W_c,
               const float* __restrict__ W_f, const float* __restrict__ W_r,
               const float* __restrict__ b_t, const float* __restrict__ b_c,
               const float* __restrict__ b_f, const float* __restrict__ b_r,
               __hip_bfloat16* __restrict__ W1bf, __hip_bfloat16* __restrict__ W2bf,
               __hip_bfloat16* __restrict__ BtH, __hip_bfloat16* __restrict__ BtM,
               __hip_bfloat16* __restrict__ BtL, float* __restrict__ bsum)
{
  const int b = blockIdx.x, tid = threadIdx.x;
  if (b < 64) {                       // W1 [128k][512n] -> W1bf[n][k]
    const int n0 = b * 8;
    for (int e = tid; e < 1024; e += 256) {
      int n_l = e & 7, k = e >> 3;
      W1bf[(size_t)(n0 + n_l) * 128 + k] = __float2bfloat16(W1[(size_t)k * 512 + n0 + n_l]);
    }
  } else if (b < 68) {                // W2 [512k][24p] -> W2bf[p][k], rows 24..31 zero
    const int k0 = (b - 64) * 128;
    for (int e = tid; e < 4096; e += 256) {
      int p = e >> 7, k_l = e & 127;
      float v = (p < 24) ? W2[(size_t)(k0 + k_l) * 24 + p] : 0.0f;
      W2bf[(size_t)p * 512 + k0 + k_l] = __float2bfloat16(v);
    }
  } else if (b < 72) {                // Bt[d][k=st*24+s] = W_st[s][d], 3-level bf16 split
    const int st = b - 68;
    const float* src = (st == 0) ? W_t : (st == 1) ? W_c : (st == 2) ? W_f : W_r;
    for (int e = tid; e < 3072; e += 256) {
      int s = e >> 7, d = e & 127;
      float x = src[e];                       // src[s*128 + d]
      __hip_bfloat16 h = __float2bfloat16(x);
      float r1 = x - __bfloat162float(h);
      __hip_bfloat16 m = __float2bfloat16(r1);
      float r2 = r1 - __bfloat162float(m);
      const int o = d * 96 + st * 24 + s;
      BtH[o] = h;
      BtM[o] = m;
      BtL[o] = __float2bfloat16(r2);
    }
  } else {
    if (tid < 128) bsum[tid] = b_t[tid] + b_c[tid] + b_f[tid] + b_r[tid];
  }
}

// ---------------- K1a2: coalesced-staging stage1 GEMM + expmap0 -> z ----
// Block = (seg, bb): M=128 features, K=96, N=128. Staging reads 96 contiguous 512B rows
// (fully coalesced). fp32 X[96][129] in LDS; 3-level split on read (R5-verified math).
// Wave w owns f in [w*32, w*32+32): 2 m-tiles x 8 n-tiles, acc[2][8].
extern "C" __global__ __launch_bounds__(256, 3)
void mwhf_k1a2(const float* __restrict__ trend,
               const float* __restrict__ seas_c,
               const float* __restrict__ seas_f,
               const float* __restrict__ resid,
               const __hip_bfloat16* __restrict__ BtH,
               const __hip_bfloat16* __restrict__ BtM,
               const __hip_bfloat16* __restrict__ BtL,
               const float* __restrict__ bsum,
               float* __restrict__ z_ws, float* __restrict__ z2_ws)
{
  __shared__ __align__(16) float X[96 * XR];   // 49536 B

  const int tid = threadIdx.x;
  const int seg = blockIdx.x;        // 0..14
  const int bb  = blockIdx.y;        // 0..127

  // ---- stage: 96 rows x 512B, fully coalesced ----
  {
    const float* ptrs[4] = {trend, seas_c, seas_f, resid};
#pragma unroll
    for (int it = 0; it < 12; ++it) {
      int e = it * 256 + tid;          // 0..3071
      int row = e >> 5;                // 0..95  (k index)
      int fq = (e & 31) * 4;
      int st = row / 24, sI = row - st * 24;
      float4 v = *(const float4*)&ptrs[st][(size_t)(bb * kL + kT0off + seg * 24 + sI) * kF + fq];
      float* dst = &X[row * XR + fq];
      dst[0] = v.x; dst[1] = v.y; dst[2] = v.z; dst[3] = v.w;
    }
  }
  __syncthreads();

  const int w = tid >> 6, lane = tid & 63;
  const int l16 = lane & 15, quad = lane >> 4;
  const int fbase = w * 32;

  // ---- GEMM: acc[s][t] over k-steps; A split-on-read from fp32 LDS ----
  f32x4 acc[2][8];
#pragma unroll
  for (int s = 0; s < 2; ++s)
#pragma unroll
    for (int t = 0; t < 8; ++t) acc[s][t] = (f32x4)0.f;

  const __hip_bfloat16* bhp = BtH + l16 * 96 + quad * 8;
  const __hip_bfloat16* bmp = BtM + l16 * 96 + quad * 8;
  const __hip_bfloat16* blp = BtL + l16 * 96 + quad * 8;

#pragma unroll
  for (int ks = 0; ks < 3; ++ks) {
    s16x8 ah[2], am[2], al[2];
#pragma unroll
    for (int s = 0; s < 2; ++s) {
      const int f = fbase + s * 16 + l16;
      const float* ar = &X[(ks * 32 + quad * 8) * XR + f];
#pragma unroll
      for (int j = 0; j < 8; ++j) {
        float x = ar[j * XR];
        unsigned hu = __float_as_uint(x) & 0xFFFF0000u;
        float r1 = x - __uint_as_float(hu);
        float mf; unsigned short mb = rne_bf16(r1, mf);
        float r2 = r1 - mf;
        float lf; unsigned short lb = rne_bf16(r2, lf);
        (void)lf;
        ah[s][j] = (short)(hu >> 16);
        am[s][j] = (short)mb;
        al[s][j] = (short)lb;
      }
    }
#pragma unroll
    for (int t = 0; t < 8; ++t) {
      s16x8 bh = *(const s16x8*)(bhp + t * 1536 + ks * 32);
      s16x8 bm = *(const s16x8*)(bmp + t * 1536 + ks * 32);
      s16x8 bl = *(const s16x8*)(blp + t * 1536 + ks * 32);
#pragma unroll
      for (int s = 0; s < 2; ++s) {
        acc[s][t] = __builtin_amdgcn_mfma_f32_16x16x32_bf16(ah[s], bh, acc[s][t], 0, 0, 0);
        acc[s][t] = __builtin_amdgcn_mfma_f32_16x16x32_bf16(am[s], bh, acc[s][t], 0, 0, 0);
        acc[s][t] = __builtin_amdgcn_mfma_f32_16x16x32_bf16(ah[s], bm, acc[s][t], 0, 0, 0);
        acc[s][t] = __builtin_amdgcn_mfma_f32_16x16x32_bf16(al[s], bh, acc[s][t], 0, 0, 0);
        acc[s][t] = __builtin_amdgcn_mfma_f32_16x16x32_bf16(ah[s], bl, acc[s][t], 0, 0, 0);
        acc[s][t] = __builtin_amdgcn_mfma_f32_16x16x32_bf16(am[s], bm, acc[s][t], 0, 0, 0);
      }
    }
  }

  // ---- epilogue: bias, row-norm (over d = t,l16), expmap0 scale, write z ----
  float part[2][4] = {{0.f,0.f,0.f,0.f},{0.f,0.f,0.f,0.f}};
#pragma unroll
  for (int t = 0; t < 8; ++t) {
    float bv = bsum[t * 16 + l16];
#pragma unroll
    for (int s = 0; s < 2; ++s)
#pragma unroll
      for (int r = 0; r < 4; ++r) {
        float v = acc[s][t][r] + bv;
        acc[s][t][r] = v;
        part[s][r] += v * v;
      }
  }
#pragma unroll
  for (int s = 0; s < 2; ++s)
#pragma unroll
    for (int r = 0; r < 4; ++r) part[s][r] = sum16(part[s][r]);

#pragma unroll
  for (int s = 0; s < 2; ++s)
#pragma unroll
    for (int r = 0; r < 4; ++r) {
      const int f = fbase + s * 16 + quad * 4 + r;
      float v2 = part[s][r];
      float nv = sqrt_f(fmaxf(v2, 1e-12f));
      float sc = tanh_f(nv) * rcp_f(nv);
      float y2 = sc * sc * v2;
      float yn = sqrt_f(fmaxf(y2, 1e-12f));
      float proj = (yn > kMaxN) ? (kMaxN * rcp_f(yn)) : 1.0f;
      float scl = sc * proj;
      float* zr = z_ws + (size_t)(bb * 128 + f) * 1920 + seg * 128;
#pragma unroll
      for (int t = 0; t < 8; ++t)
        zr[t * 16 + l16] = acc[s][t][r] * scl;
      if (l16 == 0) z2_ws[(bb * 128 + f) * 16 + seg] = y2 * proj * proj;
    }
}

// ---------------- K1b (R5-verified): hyperbolic recurrence, barrier-free, high-TLP ----
extern "C" __global__ __launch_bounds__(256, 6)
void mwhf_k1b(const float* __restrict__ z_ws, const float* __restrict__ z2_ws,
              const float* __restrict__ alpha,
              __hip_bfloat16* __restrict__ t0_out)
{
  __shared__ float z2s[80];
  __shared__ float pds[80];
  const int tid = threadIdx.x;
  const int w = tid >> 6, l = tid & 63;
  const int ro = blockIdx.x * 4 + w;

  float zx[19], zy[19];
  const float* zr = z_ws + (size_t)ro * 1920;
#pragma unroll
  for (int j = 0; j < 15; ++j) {
    float2 v = *(const float2*)&zr[j * 128 + 2 * l];
    zx[j] = v.x; zy[j] = v.y;
  }
  if (l < 15) z2s[w * 20 + l] = z2_ws[ro * 16 + l];

  {
    float pd[14];
#pragma unroll
    for (int j = 0; j < 14; ++j) pd[j] = zx[j] * zx[j + 1] + zy[j] * zy[j + 1];
#pragma unroll
    for (int j = 0; j < 14; ++j) pd[j] = sum64(pd[j]);
    if (l == 0) {
#pragma unroll
      for (int j = 0; j < 14; ++j) pds[w * 20 + j] = pd[j];
    }
  }

  const float alp = alpha[0];
  const float cw14 = (l < 14)
      ? __builtin_amdgcn_exp2f((float)(13 - l) * -0.15200309344504997f) * 0.12966260f
      : 0.f;

#pragma unroll
  for (int it = 0; it < 4; ++it) {
    float cA = 0.f, cB = 0.f, cW = 0.f;
    if (l < 14) {
      float dp = pds[w * 20 + it + l];
      float x2 = z2s[w * 20 + it + l];
      float y2 = z2s[w * 20 + it + l + 1];
      cA = 1.f - 2.f * dp + y2;
      cB = 1.f - x2;
      float den = fmaxf(1.f - 2.f * dp + x2 * y2, kEps);
      float invd = rcp_f(den);
      float d2 = (cA * cA * x2 - 2.f * cA * cB * dp + cB * cB * y2) * (invd * invd);
      float n = sqrt_f(fmaxf(d2, 1e-12f));
      float coef = fmaxf(cB, kEps) * artanh_f(n) * rcp_f(n);
      cW = cw14 * coef * invd;
    }
    float avx = 0.f, avy = 0.f;
#pragma unroll
    for (int i = 0; i < 14; ++i) {
      float sA = rlane(cA, i), sB = rlane(cB, i), sW = rlane(cW, i);
      float tx = sB * zx[it + i + 1] - sA * zx[it + i];
      float ty = sB * zy[it + i + 1] - sA * zy[it + i];
      avx += sW * tx;
      avy += sW * ty;
    }
    float vx = alp * avx, vy = alp * avy;
    const int pl = it + 14;
    float x2l = z2s[w * 20 + pl];
    float v2 = vx * vx + vy * vy;
    float xdv = zx[pl] * vx + zy[pl] * vy;
    v2 = sum64(v2);
    xdv = sum64(xdv);
    float nv = sqrt_f(fmaxf(v2, 1e-12f));
    float lam = 2.f * rcp_f(fmaxf(1.f - x2l, kEps));
    float co = tanh_f(0.5f * lam * nv) * rcp_f(nv);
    float s2 = co * co * v2;
    float xy = co * xdv;
    float P = 1.f + 2.f * xy + s2;
    float Q = 1.f - x2l;
    float den2 = fmaxf(1.f + 2.f * xy + x2l * s2, kEps);
    float invd2 = rcp_f(den2);
    float znx = (P * zx[pl] + Q * co * vx) * invd2;
    float zny = (P * zy[pl] + Q * co * vy) * invd2;
    float zn2 = (P * P * x2l + 2.f * P * Q * xy + Q * Q * s2) * (invd2 * invd2);
    float pdn = (P * x2l + Q * xy) * invd2;
    float yn = sqrt_f(fmaxf(zn2, 1e-12f));
    float proj = (yn > kMaxN) ? (kMaxN * rcp_f(yn)) : 1.f;
    znx *= proj; zny *= proj;
    zn2 *= proj * proj;
    pdn *= proj;
    zx[15 + it] = znx; zy[15 + it] = zny;
    if (l == 0) {
      z2s[w * 20 + 15 + it] = zn2;
      pds[w * 20 + 14 + it] = pdn;
    }
    float n0 = sqrt_f(fmaxf(zn2, 1e-12f));
    float fac = artanh_f(n0) * rcp_f(n0);
    __hip_bfloat162 hv;
    hv.x = __float2bfloat16(fac * znx);
    hv.y = __float2bfloat16(fac * zny);
    *(__hip_bfloat162*)(t0_out + ((size_t)ro * 4 + it) * 128 + 2 * l) = hv;
  }
}

// ---------------- fused K1 (R4/R6-verified) fallback if ws too small for z ----------------
extern "C" __global__ __launch_bounds__(256, 4)
void mwhf_k1(const float* __restrict__ trend,
             const float* __restrict__ seas_c,
             const float* __restrict__ seas_f,
             const float* __restrict__ resid,
             const __hip_bfloat16* __restrict__ BtH,
             const __hip_bfloat16* __restrict__ BtM,
             const __hip_bfloat16* __restrict__ BtL,
             const float* __restrict__ bsum,
             const float* __restrict__ alpha,
             __hip_bfloat16* __restrict__ t0_out)
{
  __shared__ __align__(16) char smem_raw[3 * 64 * AROW * 2];
  __shared__ float z2s[80];
  __shared__ float pds[80];

  float* ublk = (float*)smem_raw;
  __hip_bfloat16* Ah = (__hip_bfloat16*)smem_raw;
  __hip_bfloat16* Am = Ah + 64 * AROW;
  __hip_bfloat16* Al = Am + 64 * AROW;

  const int tid = threadIdx.x;
  const int bix = blockIdx.x;
  const int bb = (bix & 7) * 16 + (bix >> 8);
  const int f0 = ((bix >> 3) & 31) * 4;
  const int row0 = bb * 128 + f0;

  for (int e = tid; e < 192; e += 256) {
    int rr = e / 48, cc = e - rr * 48;
    int off = (rr * 16 + 15) * AROW;
    ((unsigned int*)(Ah + off))[cc] = 0u;
    ((unsigned int*)(Am + off))[cc] = 0u;
    ((unsigned int*)(Al + off))[cc] = 0u;
  }
  {
    const float* ptrs[4] = {trend, seas_c, seas_f, resid};
    for (int e = tid; e < 1440; e += 256) {
      int seg = e / 96;
      int k = e - seg * 96;
      int st = k / 24, s = k - st * 24;
      const float* p = ptrs[st];
      float4 v = *(const float4*)&p[(size_t)(bb * kL + kT0off + seg * 24 + s) * kF + f0];
      float xv[4] = {v.x, v.y, v.z, v.w};
#pragma unroll
      for (int f = 0; f < 4; ++f) {
        int m = f * 16 + seg;
        __hip_bfloat16 h = __float2bfloat16(xv[f]);
        float r1 = xv[f] - __bfloat162float(h);
        __hip_bfloat16 mm = __float2bfloat16(r1);
        float r2 = r1 - __bfloat162float(mm);
        Ah[m * AROW + k] = h;
        Am[m * AROW + k] = mm;
        Al[m * AROW + k] = __float2bfloat16(r2);
      }
    }
  }
  __syncthreads();

  const int w = tid >> 6;
  const int lane = tid & 63;
  const int l16 = lane & 15, quad = lane >> 4;

  f32x4 acc0[8];
  float scale4[4], zz4[4];
  {
    s16x8 ah[3], am[3], al[3];
    const int abase = (w * 16 + l16) * AROW + quad * 8;
#pragma unroll
    for (int ks = 0; ks < 3; ++ks) {
      ah[ks] = *(const s16x8*)(Ah + abase + ks * 32);
      am[ks] = *(const s16x8*)(Am + abase + ks * 32);
      al[ks] = *(const s16x8*)(Al + abase + ks * 32);
    }
#pragma unroll
    for (int t = 0; t < 8; ++t) acc0[t] = (f32x4)0.f;
    const __hip_bfloat16* bhp = BtH + l16 * 96 + quad * 8;
    const __hip_bfloat16* bmp = BtM + l16 * 96 + quad * 8;
    const __hip_bfloat16* blp = BtL + l16 * 96 + quad * 8;
#pragma unroll
    for (int t = 0; t < 8; ++t) {
#pragma unroll
      for (int ks = 0; ks < 3; ++ks) {
        s16x8 bh = *(const s16x8*)(bhp + t * 1536 + ks * 32);
        s16x8 bm = *(const s16x8*)(bmp + t * 1536 + ks * 32);
        s16x8 bl = *(const s16x8*)(blp + t * 1536 + ks * 32);
        acc0[t] = __builtin_amdgcn_mfma_f32_16x16x32_bf16(ah[ks], bh, acc0[t], 0, 0, 0);
        acc0[t] = __builtin_amdgcn_mfma_f32_16x16x32_bf16(am[ks], bh, acc0[t], 0, 0, 0);
        acc0[t] = __builtin_amdgcn_mfma_f32_16x16x32_bf16(ah[ks], bm, acc0[t], 0, 0, 0);
        acc0[t] = __builtin_amdgcn_mfma_f32_16x16x32_bf16(al[ks], bh, acc0[t], 0, 0, 0);
        acc0[t] = __builtin_amdgcn_mfma_f32_16x16x32_bf16(ah[ks], bl, acc0[t], 0, 0, 0);
        acc0[t] = __builtin_amdgcn_mfma_f32_16x16x32_bf16(am[ks], bm, acc0[t], 0, 0, 0);
      }
    }
    float part[4] = {0.f, 0.f, 0.f, 0.f};
#pragma unroll
    for (int t = 0; t < 8; ++t) {
      float bv = bsum[t * 16 + l16];
#pragma unroll
      for (int r = 0; r < 4; ++r) {
        float v = acc0[t][r] + bv;
        acc0[t][r] = v;
        part[r] += v * v;
      }
    }
#pragma unroll
    for (int r = 0; r < 4; ++r) part[r] = sum16(part[r]);
#pragma unroll
    for (int r = 0; r < 4; ++r) {
      float v2 = part[r];
      float nv = sqrt_f(fmaxf(v2, 1e-12f));
      float sc = tanh_f(nv) * rcp_f(nv);
      float y2 = sc * sc * v2;
      float yn = sqrt_f(fmaxf(y2, 1e-12f));
      float proj = (yn > kMaxN) ? (kMaxN * rcp_f(yn)) : 1.0f;
      scale4[r] = sc * proj;
      zz4[r] = y2 * proj * proj;
    }
  }
  __syncthreads();
  {
#pragma unroll
    for (int r = 0; r < 4; ++r) {
      int row = quad * 4 + r;
      if (row < kWin) {
#pragma unroll
        for (int t = 0; t < 8; ++t)
          ublk[(w * kWin + row) * ZTR + t * 16 + l16] = acc0[t][r] * scale4[r];
        if (l16 == 0) z2s[w * 20 + row] = zz4[r];
      }
    }
  }
  __syncthreads();

  {
    const int l = lane;
    float zx[19], zy[19];
#pragma unroll
    for (int j = 0; j < 15; ++j) {
      float2 v = *(const float2*)&ublk[(w * kWin + j) * ZTR + 2 * l];
      zx[j] = v.x; zy[j] = v.y;
    }
    {
      float pd[14];
#pragma unroll
      for (int j = 0; j < 14; ++j) pd[j] = zx[j] * zx[j + 1] + zy[j] * zy[j + 1];
#pragma unroll
      for (int j = 0; j < 14; ++j) pd[j] = sum64(pd[j]);
      if (l == 0) {
#pragma unroll
        for (int j = 0; j < 14; ++j) pds[w * 20 + j] = pd[j];
      }
    }
    const float alp = alpha[0];
    const float cw14 = (l < 14)
        ? __builtin_amdgcn_exp2f((float)(13 - l) * -0.15200309344504997f) * 0.12966260f
        : 0.f;
#pragma unroll
    for (int it = 0; it < 4; ++it) {
      float cA = 0.f, cB = 0.f, cW = 0.f;
      if (l < 14) {
        float dp = pds[w * 20 + it + l];
        float x2 = z2s[w * 20 + it + l];
        float y2 = z2s[w * 20 + it + l + 1];
        cA = 1.f - 2.f * dp + y2;
        cB = 1.f - x2;
        float den = fmaxf(1.f - 2.f * dp + x2 * y2, kEps);
        float invd = rcp_f(den);
        float d2 = (cA * cA * x2 - 2.f * cA * cB * dp + cB * cB * y2) * (invd * invd);
        float n = sqrt_f(fmaxf(d2, 1e-12f));
        float coef = fmaxf(cB, kEps) * artanh_f(n) * rcp_f(n);
        cW = cw14 * coef * invd;
      }
      float avx = 0.f, avy = 0.f;
#pragma unroll
      for (int i = 0; i < 14; ++i) {
        float sA = rlane(cA, i), sB = rlane(cB, i), sW = rlane(cW, i);
        float tx = sB * zx[it + i + 1] - sA * zx[it + i];
        float ty = sB * zy[it + i + 1] - sA * zy[it + i];
        avx += sW * tx;
        avy += sW * ty;
      }
      float vx = alp * avx, vy = alp * avy;
      const int pl = it + 14;
      float x2l = z2s[w * 20 + pl];
      float v2 = vx * vx + vy * vy;
      float xdv = zx[pl] * vx + zy[pl] * vy;
      v2 = sum64(v2);
      xdv = sum64(xdv);
      float nv = sqrt_f(fmaxf(v2, 1e-12f));
      float lam = 2.f * rcp_f(fmaxf(1.f - x2l, kEps));
      float co = tanh_f(0.5f * lam * nv) * rcp_f(nv);
      float s2 = co * co * v2;
      float xy = co * xdv;
      float P = 1.f + 2.f * xy + s2;
      float Q = 1.f - x2l;
      float den2 = fmaxf(1.f + 2.f * xy + x2l * s2, kEps);
      float invd2 = rcp_f(den2);
      float znx = (P * zx[pl] + Q * co * vx) * invd2;
      float zny = (P * zy[pl] + Q * co * vy) * invd2;
      float zn2 = (P * P * x2l + 2.f * P * Q * xy + Q * Q * s2) * (invd2 * invd2);
      float pdn = (P * x2l + Q * xy) * invd2;
      float yn = sqrt_f(fmaxf(zn2, 1e-12f));
      float proj = (yn > kMaxN) ? (kMaxN * rcp_f(yn)) : 1.f;
      znx *= proj; zny *= proj;
      zn2 *= proj * proj;
      pdn *= proj;
      zx[15 + it] = znx; zy[15 + it] = zny;
      if (l == 0) {
        z2s[w * 20 + 15 + it] = zn2;
        pds[w * 20 + 14 + it] = pdn;
      }
      float n0 = sqrt_f(fmaxf(zn2, 1e-12f));
      float fac = artanh_f(n0) * rcp_f(n0);
      __hip_bfloat162 hv;
      hv.x = __float2bfloat16(fac * znx);
      hv.y = __float2bfloat16(fac * zny);
      *(__hip_bfloat162*)(t0_out + ((size_t)(row0 + w) * 4 + it) * 128 + 2 * l) = hv;
    }
  }
}

// ---------------- K2g (R6-verified): fused out = relu(t0 @ W1 + b1) @ W2 + b2 ----------------
extern "C" __global__ __launch_bounds__(256, 4)
void mwhf_k2g(const __hip_bfloat16* __restrict__ t0g,
              const __hip_bfloat16* __restrict__ W1bf,
              const __hip_bfloat16* __restrict__ W2bf,
              const float* __restrict__ b1, const float* __restrict__ b2,
              float* __restrict__ outp)
{
  __shared__ __align__(16) __hip_bfloat16 hids[32 * 512];   // 32 KiB, XOR-swizzled
  s16x8* hidv = (s16x8*)hids;

  const int tid = threadIdx.x;
  const int w = tid >> 6, lane = tid & 63;
  const int l16 = lane & 15, quad = lane >> 4;
  const int mbase = blockIdx.x * 32;
  const int ng = w * 128;

  s16x8 afr[2][4];
#pragma unroll
  for (int s = 0; s < 2; ++s)
#pragma unroll
    for (int kc = 0; kc < 4; ++kc)
      afr[s][kc] = *(const s16x8*)(t0g + (size_t)(mbase + s * 16 + l16) * 128 + kc * 32 + quad * 8);

  f32x4 acc[2][8];
#pragma unroll
  for (int s = 0; s < 2; ++s)
#pragma unroll
    for (int t = 0; t < 8; ++t) acc[s][t] = (f32x4)0.f;

#pragma unroll
  for (int t = 0; t < 8; ++t) {
    const __hip_bfloat16* bp = W1bf + (size_t)(ng + t * 16 + l16) * 128 + quad * 8;
#pragma unroll
    for (int kc = 0; kc < 4; ++kc) {
      s16x8 bfr = *(const s16x8*)(bp + kc * 32);
      acc[0][t] = __builtin_amdgcn_mfma_f32_16x16x32_bf16(afr[0][kc], bfr, acc[0][t], 0, 0, 0);
      acc[1][t] = __builtin_amdgcn_mfma_f32_16x16x32_bf16(afr[1][kc], bfr, acc[1][t], 0, 0, 0);
    }
  }
#pragma unroll
  for (int t = 0; t < 8; ++t) {
    const int nl = ng + t * 16 + l16;
    float bv = b1[nl];
#pragma unroll
    for (int s = 0; s < 2; ++s)
#pragma unroll
      for (int r = 0; r < 4; ++r) {
        int m = s * 16 + quad * 4 + r;
        float h = fmaxf(acc[s][t][r] + bv, 0.f);
        hids[m * 512 + (nl ^ ((m & 7) << 3))] = __float2bfloat16(h);
      }
  }
  __syncthreads();

  {
    const int s2i = w & 1, t2 = w >> 1;
    f32x4 a2 = (f32x4)0.f;
    const int mrow = s2i * 16 + l16;
#pragma unroll 4
    for (int kc = 0; kc < 16; ++kc) {
      s16x8 av = hidv[mrow * 64 + ((kc * 4 + quad) ^ (l16 & 7))];
      s16x8 bfr = *(const s16x8*)(W2bf + (size_t)(t2 * 16 + l16) * 512 + kc * 32 + quad * 8);
      a2 = __builtin_amdgcn_mfma_f32_16x16x32_bf16(av, bfr, a2, 0, 0, 0);
    }
    const int p = t2 * 16 + l16;
    if (p < 24) {
      float bv = b2[p];
#pragma unroll
      for (int r = 0; r < 4; ++r) {
        int m = mbase + s2i * 16 + quad * 4 + r;
        int bbi = m >> 9, it = m & 3, f = (m >> 2) & 127;
        outp[(size_t)bbi * 12288 + (it * 24 + p) * 128 + f] = a2[r] + bv;
      }
    }
  }
}

extern "C" void kernel_launch(void* const* d_in, const int* in_sizes, int n_in,
                              void* d_out, int out_size, void* d_ws, size_t ws_size,
                              hipStream_t stream) {
  (void)in_sizes; (void)n_in; (void)out_size;
  const float* trend = (const float*)d_in[0];
  const float* sc    = (const float*)d_in[1];
  const float* sf    = (const float*)d_in[2];
  const float* rs    = (const float*)d_in[3];
  const float* W_t   = (const float*)d_in[4];
  const float* b_t   = (const float*)d_in[5];
  const float* W_c   = (const float*)d_in[6];
  const float* b_c   = (const float*)d_in[7];
  const float* W_f   = (const float*)d_in[8];
  const float* b_f   = (const float*)d_in[9];
  const float* W_r   = (const float*)d_in[10];
  const float* b_r   = (const float*)d_in[11];
  const float* alpha = (const float*)d_in[12];
  const float* W1    = (const float*)d_in[13];
  const float* b1    = (const float*)d_in[14];
  const float* W2    = (const float*)d_in[15];
  const float* b2    = (const float*)d_in[16];

  char* ws = (char*)d_ws;
  __hip_bfloat16* t0   = (__hip_bfloat16*)(ws + kOffT0);
  __hip_bfloat16* W1bf = (__hip_bfloat16*)(ws + kOffW1);
  __hip_bfloat16* W2bf = (__hip_bfloat16*)(ws + kOffW2);
  __hip_bfloat16* BtH  = (__hip_bfloat16*)(ws + kOffBt);
  __hip_bfloat16* BtM  = BtH + 12288;
  __hip_bfloat16* BtL  = BtM + 12288;
  float* bsum = (float*)(ws + kOffBsum);
  float* z2w  = (float*)(ws + kOffZ2);
  float* zw   = (float*)(ws + kOffZ);
  float* outp = (float*)d_out;

  hipLaunchKernelGGL(mwhf_prep, dim3(73), dim3(256), 0, stream,
                     W1, W2, W_t, W_c, W_f, W_r, b_t, b_c, b_f, b_r,
                     W1bf, W2bf, BtH, BtM, BtL, bsum);
  if (ws_size >= kWsNew) {
    hipLaunchKernelGGL(mwhf_k1a2, dim3(15, 128), dim3(256), 0, stream,
                       trend, sc, sf, rs, BtH, BtM, BtL, bsum, zw, z2w);
    hipLaunchKernelGGL(mwhf_k1b, dim3(4096), dim3(256), 0, stream,
                       zw, z2w, alpha, t0);
  } else {
    hipLaunchKernelGGL(mwhf_k1, dim3(4096), dim3(256), 0, stream,
                       trend, sc, sf, rs, BtH, BtM, BtL, bsum, alpha, t0);
  }
  hipLaunchKernelGGL(mwhf_k2g, dim3(2048), dim3(256), 0, stream,
                     t0, W1bf, W2bf, b1, b2, outp);
}

// Round 8
// 349.492 us; speedup vs baseline: 1.0723x; 1.0723x over previous
//
#include <hip/hip_runtime.h>
#include <hip/hip_bf16.h>

namespace {
constexpr int kL = 720, kF = 128;
constexpr int kWin = 15;
constexpr float kEps = 1e-6f;
constexpr float kMaxN = 1.0f - 1e-5f;
constexpr int kT0off = 360;   // (30-15)*24: only last 15 segments matter
constexpr int ZTR = 132;      // zt row stride (floats), +4 pad (fused fallback)
constexpr int AROW = 104;     // A lds row stride bf16 (fused fallback)
constexpr int XR2 = 65;       // k1a3 fp32 X row stride (64 + 1)
// ws offsets
constexpr size_t kOffT0   = 0;                    // 16 MiB bf16 t0 (fallback path only)
constexpr size_t kOffW1   = 16777216;             // 128 KiB bf16 W1 [n][k]
constexpr size_t kOffW2   = kOffW1 + 131072;      // 32 KiB bf16 W2 [p][k]
constexpr size_t kOffBt   = kOffW2 + 32768;       // 72 KiB: BtH/BtM/BtL [128][96] bf16
constexpr size_t kOffBsum = kOffBt + 73728;       // 512 B fp32
constexpr size_t kOffZ2   = 17018880;             // 1 MiB fp32 z2 [16384][16]
constexpr size_t kOffZ    = 18874368;             // 126 MiB fp32 z [16384][15][128]
constexpr size_t kWsNew   = kOffZ + 125829120;    // 144,703,488 (verified present R5/R7)
}

typedef float f32x4 __attribute__((ext_vector_type(4)));
typedef short s16x8 __attribute__((ext_vector_type(8)));

__device__ __forceinline__ float rcp_f(float x) { return __builtin_amdgcn_rcpf(x); }
__device__ __forceinline__ float sqrt_f(float x) { return __builtin_amdgcn_sqrtf(x); }
__device__ __forceinline__ float tanh_f(float x) {          // x >= 0
  float t = __builtin_amdgcn_exp2f(x * -2.8853900817779268f);
  return (1.0f - t) * rcp_f(1.0f + t);
}
__device__ __forceinline__ float artanh_f(float n) {        // n >= 0
  float nc = fminf(n, 1.0f - 1e-7f);
  return 0.34657359027997264f * __builtin_amdgcn_logf((1.0f + nc) * rcp_f(1.0f - nc));
}

// DPP butterfly add helpers (VALU-latency cross-lane, no LDS pipe).
template<int CTRL>
__device__ __forceinline__ float dpp_add(float v) {
  int mv = __builtin_amdgcn_update_dpp(0, __float_as_int(v), CTRL, 0xF, 0xF, false);
  return v + __int_as_float(mv);
}
__device__ __forceinline__ float sum16(float v) {
  v = dpp_add<0xB1>(v);
  v = dpp_add<0x4E>(v);
  v = dpp_add<0x141>(v);
  v = dpp_add<0x128>(v);
  return v;
}
__device__ __forceinline__ float sum64(float v) {
  v = sum16(v);
  v += __shfl_xor(v, 16);
  v += __shfl_xor(v, 32);
  return v;
}
__device__ __forceinline__ float rlane(float v, int i) {
  return __int_as_float(__builtin_amdgcn_readlane(__float_as_int(v), i));
}
// RNE bf16: returns 16-bit pattern, and the rounded value as f32 via fval.
__device__ __forceinline__ unsigned short rne_bf16(float f, float& fval) {
  unsigned u = __float_as_uint(f);
  unsigned r = (u + 0x7FFFu + ((u >> 16) & 1u)) & 0xFFFF0000u;
  fval = __uint_as_float(r);
  return (unsigned short)(r >> 16);
}

// ---------------- prep: weight repack (bf16 W1/W2 + 3-level split Bt + bsum) ----------------
extern "C" __global__ __launch_bounds__(256)
void mwhf_prep(const float* __restrict__ W1, const float* __restrict__ W2,
               const float* __restrict__ W_t, const float* __restrict__ W_c,
               const float* __restrict__ W_f, const float* __restrict__ W_r,
               const float* __restrict__ b_t, const float* __restrict__ b_c,
               const float* __restrict__ b_f, const float* __restrict__ b_r,
               __hip_bfloat16* __restrict__ W1bf, __hip_bfloat16* __restrict__ W2bf,
               __hip_bfloat16* __restrict__ BtH, __hip_bfloat16* __restrict__ BtM,
               __hip_bfloat16* __restrict__ BtL, float* __restrict__ bsum)
{
  const int b = blockIdx.x, tid = threadIdx.x;
  if (b < 64) {                       // W1 [128k][512n] -> W1bf[n][k]
    const int n0 = b * 8;
    for (int e = tid; e < 1024; e += 256) {
      int n_l = e & 7, k = e >> 3;
      W1bf[(size_t)(n0 + n_l) * 128 + k] = __float2bfloat16(W1[(size_t)k * 512 + n0 + n_l]);
    }
  } else if (b < 68) {                // W2 [512k][24p] -> W2bf[p][k], rows 24..31 zero
    const int k0 = (b - 64) * 128;
    for (int e = tid; e < 4096; e += 256) {
      int p = e >> 7, k_l = e & 127;
      float v = (p < 24) ? W2[(size_t)(k0 + k_l) * 24 + p] : 0.0f;
      W2bf[(size_t)p * 512 + k0 + k_l] = __float2bfloat16(v);
    }
  } else if (b < 72) {                // Bt[d][k=st*24+s] = W_st[s][d], 3-level bf16 split
    const int st = b - 68;
    const float* src = (st == 0) ? W_t : (st == 1) ? W_c : (st == 2) ? W_f : W_r;
    for (int e = tid; e < 3072; e += 256) {
      int s = e >> 7, d = e & 127;
      float x = src[e];                       // src[s*128 + d]
      __hip_bfloat16 h = __float2bfloat16(x);
      float r1 = x - __bfloat162float(h);
      __hip_bfloat16 m = __float2bfloat16(r1);
      float r2 = r1 - __bfloat162float(m);
      const int o = d * 96 + st * 24 + s;
      BtH[o] = h;
      BtM[o] = m;
      BtL[o] = __float2bfloat16(r2);
    }
  } else {
    if (tid < 128) bsum[tid] = b_t[tid] + b_c[tid] + b_f[tid] + b_r[tid];
  }
}

// ---------------- K1a3: M=64 coalesced-staging stage1 GEMM + expmap0 -> z ----
// Block = (seg, bh): M=64 features (half of one bb row), K=96, N=128.
// X[96][65] fp32 = 25.0 KB -> 6 blocks/CU by LDS; wave w owns f-tile [w*16, w*16+16).
extern "C" __global__ __launch_bounds__(256, 4)
void mwhf_k1a3(const float* __restrict__ trend,
               const float* __restrict__ seas_c,
               const float* __restrict__ seas_f,
               const float* __restrict__ resid,
               const __hip_bfloat16* __restrict__ BtH,
               const __hip_bfloat16* __restrict__ BtM,
               const __hip_bfloat16* __restrict__ BtL,
               const float* __restrict__ bsum,
               float* __restrict__ z_ws, float* __restrict__ z2_ws)
{
  __shared__ __align__(16) float X[96 * XR2];   // 24960 B

  const int tid = threadIdx.x;
  const int seg = blockIdx.x;        // 0..14
  const int bh  = blockIdx.y;        // 0..255
  const int bb  = bh >> 1;
  const int fh  = (bh & 1) * 64;

  // ---- stage: 96 rows x 256B contiguous, coalesced ----
  {
    const float* ptrs[4] = {trend, seas_c, seas_f, resid};
#pragma unroll
    for (int it = 0; it < 6; ++it) {
      int e = it * 256 + tid;          // 0..1535
      int row = e >> 4;                // 0..95  (k index)
      int fq = (e & 15) * 4;
      int st = row / 24, sI = row - st * 24;
      float4 v = *(const float4*)&ptrs[st][(size_t)(bb * kL + kT0off + seg * 24 + sI) * kF + fh + fq];
      float* dst = &X[row * XR2 + fq];
      dst[0] = v.x; dst[1] = v.y; dst[2] = v.z; dst[3] = v.w;
    }
  }
  __syncthreads();

  const int w = tid >> 6, lane = tid & 63;
  const int l16 = lane & 15, quad = lane >> 4;

  f32x4 acc[8];
#pragma unroll
  for (int t = 0; t < 8; ++t) acc[t] = (f32x4)0.f;

  const __hip_bfloat16* bhp = BtH + l16 * 96 + quad * 8;
  const __hip_bfloat16* bmp = BtM + l16 * 96 + quad * 8;
  const __hip_bfloat16* blp = BtL + l16 * 96 + quad * 8;

#pragma unroll
  for (int ks = 0; ks < 3; ++ks) {
    s16x8 ah, am, al;
    {
      const float* ar = &X[(ks * 32 + quad * 8) * XR2 + w * 16 + l16];
#pragma unroll
      for (int j = 0; j < 8; ++j) {
        float x = ar[j * XR2];
        unsigned hu = __float_as_uint(x) & 0xFFFF0000u;
        float r1 = x - __uint_as_float(hu);
        float mf; unsigned short mb = rne_bf16(r1, mf);
        float r2 = r1 - mf;
        float lf; unsigned short lb = rne_bf16(r2, lf);
        (void)lf;
        ah[j] = (short)(hu >> 16);
        am[j] = (short)mb;
        al[j] = (short)lb;
      }
    }
#pragma unroll
    for (int t = 0; t < 8; ++t) {
      s16x8 bhv = *(const s16x8*)(bhp + t * 1536 + ks * 32);
      s16x8 bmv = *(const s16x8*)(bmp + t * 1536 + ks * 32);
      s16x8 blv = *(const s16x8*)(blp + t * 1536 + ks * 32);
      acc[t] = __builtin_amdgcn_mfma_f32_16x16x32_bf16(ah, bhv, acc[t], 0, 0, 0);
      acc[t] = __builtin_amdgcn_mfma_f32_16x16x32_bf16(am, bhv, acc[t], 0, 0, 0);
      acc[t] = __builtin_amdgcn_mfma_f32_16x16x32_bf16(ah, bmv, acc[t], 0, 0, 0);
      acc[t] = __builtin_amdgcn_mfma_f32_16x16x32_bf16(al, bhv, acc[t], 0, 0, 0);
      acc[t] = __builtin_amdgcn_mfma_f32_16x16x32_bf16(ah, blv, acc[t], 0, 0, 0);
      acc[t] = __builtin_amdgcn_mfma_f32_16x16x32_bf16(am, bmv, acc[t], 0, 0, 0);
    }
  }

  // ---- epilogue: bias, row-norm over d, expmap0 scale, write z ----
  float part[4] = {0.f, 0.f, 0.f, 0.f};
#pragma unroll
  for (int t = 0; t < 8; ++t) {
    float bv = bsum[t * 16 + l16];
#pragma unroll
    for (int r = 0; r < 4; ++r) {
      float v = acc[t][r] + bv;
      acc[t][r] = v;
      part[r] += v * v;
    }
  }
#pragma unroll
  for (int r = 0; r < 4; ++r) part[r] = sum16(part[r]);

#pragma unroll
  for (int r = 0; r < 4; ++r) {
    const int row = bh * 64 + w * 16 + quad * 4 + r;   // global row 0..16383
    float v2 = part[r];
    float nv = sqrt_f(fmaxf(v2, 1e-12f));
    float sc = tanh_f(nv) * rcp_f(nv);
    float y2 = sc * sc * v2;
    float yn = sqrt_f(fmaxf(y2, 1e-12f));
    float proj = (yn > kMaxN) ? (kMaxN * rcp_f(yn)) : 1.0f;
    float scl = sc * proj;
    float* zr = z_ws + (size_t)row * 1920 + seg * 128;
#pragma unroll
    for (int t = 0; t < 8; ++t)
      zr[t * 16 + l16] = acc[t][r] * scl;
    if (l16 == 0) z2_ws[row * 16 + seg] = y2 * proj * proj;
  }
}

// ---------------- K1bg: fused recurrence + MLP (t0 via LDS, no global t0) ----
// 512 thr = 8 waves. Phase R: wave w = R5-verified recurrence for row ro=blk*8+w,
// t0 -> swizzled LDS tile. Phase 1/2: R6-verified k2g bodies (8-wave / 4-wave).
extern "C" __global__ __launch_bounds__(512, 4)
void mwhf_k1bg(const float* __restrict__ z_ws, const float* __restrict__ z2_ws,
               const float* __restrict__ alpha,
               const __hip_bfloat16* __restrict__ W1bf,
               const __hip_bfloat16* __restrict__ W2bf,
               const float* __restrict__ b1, const float* __restrict__ b2,
               float* __restrict__ outp)
{
  __shared__ __align__(16) __hip_bfloat16 t0s[32 * 128];   // 8 KiB, XOR-swizzled
  __shared__ __align__(16) __hip_bfloat16 hids[32 * 512];  // 32 KiB, XOR-swizzled
  __shared__ float z2s[160];
  __shared__ float pds[160];
  s16x8* hidv = (s16x8*)hids;

  const int tid = threadIdx.x;
  const int w = tid >> 6, l = tid & 63;
  const int l16 = l & 15, quad = l >> 4;
  const int mbase = blockIdx.x * 32;

  // ---- phase R: recurrence (verbatim R5 k1b body, 8 waves, 1 row each) ----
  {
    const int ro = blockIdx.x * 8 + w;
    float zx[19], zy[19];
    const float* zr = z_ws + (size_t)ro * 1920;
#pragma unroll
    for (int j = 0; j < 15; ++j) {
      float2 v = *(const float2*)&zr[j * 128 + 2 * l];
      zx[j] = v.x; zy[j] = v.y;
    }
    if (l < 15) z2s[w * 20 + l] = z2_ws[ro * 16 + l];

    {
      float pd[14];
#pragma unroll
      for (int j = 0; j < 14; ++j) pd[j] = zx[j] * zx[j + 1] + zy[j] * zy[j + 1];
#pragma unroll
      for (int j = 0; j < 14; ++j) pd[j] = sum64(pd[j]);
      if (l == 0) {
#pragma unroll
        for (int j = 0; j < 14; ++j) pds[w * 20 + j] = pd[j];
      }
    }

    const float alp = alpha[0];
    const float cw14 = (l < 14)
        ? __builtin_amdgcn_exp2f((float)(13 - l) * -0.15200309344504997f) * 0.12966260f
        : 0.f;

#pragma unroll
    for (int it = 0; it < 4; ++it) {
      float cA = 0.f, cB = 0.f, cW = 0.f;
      if (l < 14) {
        float dp = pds[w * 20 + it + l];
        float x2 = z2s[w * 20 + it + l];
        float y2 = z2s[w * 20 + it + l + 1];
        cA = 1.f - 2.f * dp + y2;
        cB = 1.f - x2;
        float den = fmaxf(1.f - 2.f * dp + x2 * y2, kEps);
        float invd = rcp_f(den);
        float d2 = (cA * cA * x2 - 2.f * cA * cB * dp + cB * cB * y2) * (invd * invd);
        float n = sqrt_f(fmaxf(d2, 1e-12f));
        float coef = fmaxf(cB, kEps) * artanh_f(n) * rcp_f(n);
        cW = cw14 * coef * invd;
      }
      float avx = 0.f, avy = 0.f;
#pragma unroll
      for (int i = 0; i < 14; ++i) {
        float sA = rlane(cA, i), sB = rlane(cB, i), sW = rlane(cW, i);
        float tx = sB * zx[it + i + 1] - sA * zx[it + i];
        float ty = sB * zy[it + i + 1] - sA * zy[it + i];
        avx += sW * tx;
        avy += sW * ty;
      }
      float vx = alp * avx, vy = alp * avy;
      const int pl = it + 14;
      float x2l = z2s[w * 20 + pl];
      float v2 = vx * vx + vy * vy;
      float xdv = zx[pl] * vx + zy[pl] * vy;
      v2 = sum64(v2);
      xdv = sum64(xdv);
      float nv = sqrt_f(fmaxf(v2, 1e-12f));
      float lam = 2.f * rcp_f(fmaxf(1.f - x2l, kEps));
      float co = tanh_f(0.5f * lam * nv) * rcp_f(nv);
      float s2 = co * co * v2;
      float xy = co * xdv;
      float P = 1.f + 2.f * xy + s2;
      float Q = 1.f - x2l;
      float den2 = fmaxf(1.f + 2.f * xy + x2l * s2, kEps);
      float invd2 = rcp_f(den2);
      float znx = (P * zx[pl] + Q * co * vx) * invd2;
      float zny = (P * zy[pl] + Q * co * vy) * invd2;
      float zn2 = (P * P * x2l + 2.f * P * Q * xy + Q * Q * s2) * (invd2 * invd2);
      float pdn = (P * x2l + Q * xy) * invd2;
      float yn = sqrt_f(fmaxf(zn2, 1e-12f));
      float proj = (yn > kMaxN) ? (kMaxN * rcp_f(yn)) : 1.f;
      znx *= proj; zny *= proj;
      zn2 *= proj * proj;
      pdn *= proj;
      zx[15 + it] = znx; zy[15 + it] = zny;
      if (l == 0) {
        z2s[w * 20 + 15 + it] = zn2;
        pds[w * 20 + 14 + it] = pdn;
      }
      float n0 = sqrt_f(fmaxf(zn2, 1e-12f));
      float fac = artanh_f(n0) * rcp_f(n0);
      __hip_bfloat162 hv;
      hv.x = __float2bfloat16(fac * znx);
      hv.y = __float2bfloat16(fac * zny);
      const int mloc = w * 4 + it;                       // local m 0..31
      const int cs = (2 * l) ^ ((mloc & 7) << 3);        // swizzled halfword col
      *(__hip_bfloat162*)&t0s[mloc * 128 + cs] = hv;
    }
  }
  __syncthreads();

  // ---- phase 1: hid = relu(t0 @ W1 + b1) -> LDS; wave w handles n in [w*64, w*64+64) ----
  {
    const int ng = w * 64;
    s16x8 afr[2][4];
#pragma unroll
    for (int s = 0; s < 2; ++s)
#pragma unroll
      for (int kc = 0; kc < 4; ++kc)
        afr[s][kc] = *(const s16x8*)&t0s[(s * 16 + l16) * 128 +
                                         ((kc * 32 + quad * 8) ^ ((l16 & 7) << 3))];

    f32x4 acc2[2][4];
#pragma unroll
    for (int s = 0; s < 2; ++s)
#pragma unroll
      for (int t = 0; t < 4; ++t) acc2[s][t] = (f32x4)0.f;

#pragma unroll
    for (int t = 0; t < 4; ++t) {
      const __hip_bfloat16* bp = W1bf + (size_t)(ng + t * 16 + l16) * 128 + quad * 8;
#pragma unroll
      for (int kc = 0; kc < 4; ++kc) {
        s16x8 bfr = *(const s16x8*)(bp + kc * 32);
        acc2[0][t] = __builtin_amdgcn_mfma_f32_16x16x32_bf16(afr[0][kc], bfr, acc2[0][t], 0, 0, 0);
        acc2[1][t] = __builtin_amdgcn_mfma_f32_16x16x32_bf16(afr[1][kc], bfr, acc2[1][t], 0, 0, 0);
      }
    }
#pragma unroll
    for (int t = 0; t < 4; ++t) {
      const int nl = ng + t * 16 + l16;
      float bv = b1[nl];
#pragma unroll
      for (int s = 0; s < 2; ++s)
#pragma unroll
        for (int r = 0; r < 4; ++r) {
          int m = s * 16 + quad * 4 + r;
          float h = fmaxf(acc2[s][t][r] + bv, 0.f);
          hids[m * 512 + (nl ^ ((m & 7) << 3))] = __float2bfloat16(h);
        }
    }
  }
  __syncthreads();

  // ---- phase 2: out = hid @ W2 + b2 (waves 0..3, verbatim k2g) ----
  if (w < 4) {
    const int s2i = w & 1, t2 = w >> 1;
    f32x4 a2 = (f32x4)0.f;
    const int mrow = s2i * 16 + l16;
#pragma unroll 4
    for (int kc = 0; kc < 16; ++kc) {
      s16x8 av = hidv[mrow * 64 + ((kc * 4 + quad) ^ (l16 & 7))];
      s16x8 bfr = *(const s16x8*)(W2bf + (size_t)(t2 * 16 + l16) * 512 + kc * 32 + quad * 8);
      a2 = __builtin_amdgcn_mfma_f32_16x16x32_bf16(av, bfr, a2, 0, 0, 0);
    }
    const int p = t2 * 16 + l16;
    if (p < 24) {
      float bv = b2[p];
#pragma unroll
      for (int r = 0; r < 4; ++r) {
        int m = mbase + s2i * 16 + quad * 4 + r;
        int bbi = m >> 9, it = m & 3, f = (m >> 2) & 127;
        outp[(size_t)bbi * 12288 + (it * 24 + p) * 128 + f] = a2[r] + bv;
      }
    }
  }
}

// ---------------- fused K1 (R4/R6-verified) fallback if ws too small for z ----------------
extern "C" __global__ __launch_bounds__(256, 4)
void mwhf_k1(const float* __restrict__ trend,
             const float* __restrict__ seas_c,
             const float* __restrict__ seas_f,
             const float* __restrict__ resid,
             const __hip_bfloat16* __restrict__ BtH,
             const __hip_bfloat16* __restrict__ BtM,
             const __hip_bfloat16* __restrict__ BtL,
             const float* __restrict__ bsum,
             const float* __restrict__ alpha,
             __hip_bfloat16* __restrict__ t0_out)
{
  __shared__ __align__(16) char smem_raw[3 * 64 * AROW * 2];
  __shared__ float z2s[80];
  __shared__ float pds[80];

  float* ublk = (float*)smem_raw;
  __hip_bfloat16* Ah = (__hip_bfloat16*)smem_raw;
  __hip_bfloat16* Am = Ah + 64 * AROW;
  __hip_bfloat16* Al = Am + 64 * AROW;

  const int tid = threadIdx.x;
  const int bix = blockIdx.x;
  const int bb = (bix & 7) * 16 + (bix >> 8);
  const int f0 = ((bix >> 3) & 31) * 4;
  const int row0 = bb * 128 + f0;

  for (int e = tid; e < 192; e += 256) {
    int rr = e / 48, cc = e - rr * 48;
    int off = (rr * 16 + 15) * AROW;
    ((unsigned int*)(Ah + off))[cc] = 0u;
    ((unsigned int*)(Am + off))[cc] = 0u;
    ((unsigned int*)(Al + off))[cc] = 0u;
  }
  {
    const float* ptrs[4] = {trend, seas_c, seas_f, resid};
    for (int e = tid; e < 1440; e += 256) {
      int seg = e / 96;
      int k = e - seg * 96;
      int st = k / 24, s = k - st * 24;
      const float* p = ptrs[st];
      float4 v = *(const float4*)&p[(size_t)(bb * kL + kT0off + seg * 24 + s) * kF + f0];
      float xv[4] = {v.x, v.y, v.z, v.w};
#pragma unroll
      for (int f = 0; f < 4; ++f) {
        int m = f * 16 + seg;
        __hip_bfloat16 h = __float2bfloat16(xv[f]);
        float r1 = xv[f] - __bfloat162float(h);
        __hip_bfloat16 mm = __float2bfloat16(r1);
        float r2 = r1 - __bfloat162float(mm);
        Ah[m * AROW + k] = h;
        Am[m * AROW + k] = mm;
        Al[m * AROW + k] = __float2bfloat16(r2);
      }
    }
  }
  __syncthreads();

  const int w = tid >> 6;
  const int lane = tid & 63;
  const int l16 = lane & 15, quad = lane >> 4;

  f32x4 acc0[8];
  float scale4[4], zz4[4];
  {
    s16x8 ah[3], am[3], al[3];
    const int abase = (w * 16 + l16) * AROW + quad * 8;
#pragma unroll
    for (int ks = 0; ks < 3; ++ks) {
      ah[ks] = *(const s16x8*)(Ah + abase + ks * 32);
      am[ks] = *(const s16x8*)(Am + abase + ks * 32);
      al[ks] = *(const s16x8*)(Al + abase + ks * 32);
    }
#pragma unroll
    for (int t = 0; t < 8; ++t) acc0[t] = (f32x4)0.f;
    const __hip_bfloat16* bhp = BtH + l16 * 96 + quad * 8;
    const __hip_bfloat16* bmp = BtM + l16 * 96 + quad * 8;
    const __hip_bfloat16* blp = BtL + l16 * 96 + quad * 8;
#pragma unroll
    for (int t = 0; t < 8; ++t) {
#pragma unroll
      for (int ks = 0; ks < 3; ++ks) {
        s16x8 bh = *(const s16x8*)(bhp + t * 1536 + ks * 32);
        s16x8 bm = *(const s16x8*)(bmp + t * 1536 + ks * 32);
        s16x8 bl = *(const s16x8*)(blp + t * 1536 + ks * 32);
        acc0[t] = __builtin_amdgcn_mfma_f32_16x16x32_bf16(ah[ks], bh, acc0[t], 0, 0, 0);
        acc0[t] = __builtin_amdgcn_mfma_f32_16x16x32_bf16(am[ks], bh, acc0[t], 0, 0, 0);
        acc0[t] = __builtin_amdgcn_mfma_f32_16x16x32_bf16(ah[ks], bm, acc0[t], 0, 0, 0);
        acc0[t] = __builtin_amdgcn_mfma_f32_16x16x32_bf16(al[ks], bh, acc0[t], 0, 0, 0);
        acc0[t] = __builtin_amdgcn_mfma_f32_16x16x32_bf16(ah[ks], bl, acc0[t], 0, 0, 0);
        acc0[t] = __builtin_amdgcn_mfma_f32_16x16x32_bf16(am[ks], bm, acc0[t], 0, 0, 0);
      }
    }
    float part[4] = {0.f, 0.f, 0.f, 0.f};
#pragma unroll
    for (int t = 0; t < 8; ++t) {
      float bv = bsum[t * 16 + l16];
#pragma unroll
      for (int r = 0; r < 4; ++r) {
        float v = acc0[t][r] + bv;
        acc0[t][r] = v;
        part[r] += v * v;
      }
    }
#pragma unroll
    for (int r = 0; r < 4; ++r) part[r] = sum16(part[r]);
#pragma unroll
    for (int r = 0; r < 4; ++r) {
      float v2 = part[r];
      float nv = sqrt_f(fmaxf(v2, 1e-12f));
      float sc = tanh_f(nv) * rcp_f(nv);
      float y2 = sc * sc * v2;
      float yn = sqrt_f(fmaxf(y2, 1e-12f));
      float proj = (yn > kMaxN) ? (kMaxN * rcp_f(yn)) : 1.0f;
      scale4[r] = sc * proj;
      zz4[r] = y2 * proj * proj;
    }
  }
  __syncthreads();
  {
#pragma unroll
    for (int r = 0; r < 4; ++r) {
      int row = quad * 4 + r;
      if (row < kWin) {
#pragma unroll
        for (int t = 0; t < 8; ++t)
          ublk[(w * kWin + row) * ZTR + t * 16 + l16] = acc0[t][r] * scale4[r];
        if (l16 == 0) z2s[w * 20 + row] = zz4[r];
      }
    }
  }
  __syncthreads();

  {
    const int l = lane;
    float zx[19], zy[19];
#pragma unroll
    for (int j = 0; j < 15; ++j) {
      float2 v = *(const float2*)&ublk[(w * kWin + j) * ZTR + 2 * l];
      zx[j] = v.x; zy[j] = v.y;
    }
    {
      float pd[14];
#pragma unroll
      for (int j = 0; j < 14; ++j) pd[j] = zx[j] * zx[j + 1] + zy[j] * zy[j + 1];
#pragma unroll
      for (int j = 0; j < 14; ++j) pd[j] = sum64(pd[j]);
      if (l == 0) {
#pragma unroll
        for (int j = 0; j < 14; ++j) pds[w * 20 + j] = pd[j];
      }
    }
    const float alp = alpha[0];
    const float cw14 = (l < 14)
        ? __builtin_amdgcn_exp2f((float)(13 - l) * -0.15200309344504997f) * 0.12966260f
        : 0.f;
#pragma unroll
    for (int it = 0; it < 4; ++it) {
      float cA = 0.f, cB = 0.f, cW = 0.f;
      if (l < 14) {
        float dp = pds[w * 20 + it + l];
        float x2 = z2s[w * 20 + it + l];
        float y2 = z2s[w * 20 + it + l + 1];
        cA = 1.f - 2.f * dp + y2;
        cB = 1.f - x2;
        float den = fmaxf(1.f - 2.f * dp + x2 * y2, kEps);
        float invd = rcp_f(den);
        float d2 = (cA * cA * x2 - 2.f * cA * cB * dp + cB * cB * y2) * (invd * invd);
        float n = sqrt_f(fmaxf(d2, 1e-12f));
        float coef = fmaxf(cB, kEps) * artanh_f(n) * rcp_f(n);
        cW = cw14 * coef * invd;
      }
      float avx = 0.f, avy = 0.f;
#pragma unroll
      for (int i = 0; i < 14; ++i) {
        float sA = rlane(cA, i), sB = rlane(cB, i), sW = rlane(cW, i);
        float tx = sB * zx[it + i + 1] - sA * zx[it + i];
        float ty = sB * zy[it + i + 1] - sA * zy[it + i];
        avx += sW * tx;
        avy += sW * ty;
      }
      float vx = alp * avx, vy = alp * avy;
      const int pl = it + 14;
      float x2l = z2s[w * 20 + pl];
      float v2 = vx * vx + vy * vy;
      float xdv = zx[pl] * vx + zy[pl] * vy;
      v2 = sum64(v2);
      xdv = sum64(xdv);
      float nv = sqrt_f(fmaxf(v2, 1e-12f));
      float lam = 2.f * rcp_f(fmaxf(1.f - x2l, kEps));
      float co = tanh_f(0.5f * lam * nv) * rcp_f(nv);
      float s2 = co * co * v2;
      float xy = co * xdv;
      float P = 1.f + 2.f * xy + s2;
      float Q = 1.f - x2l;
      float den2 = fmaxf(1.f + 2.f * xy + x2l * s2, kEps);
      float invd2 = rcp_f(den2);
      float znx = (P * zx[pl] + Q * co * vx) * invd2;
      float zny = (P * zy[pl] + Q * co * vy) * invd2;
      float zn2 = (P * P * x2l + 2.f * P * Q * xy + Q * Q * s2) * (invd2 * invd2);
      float pdn = (P * x2l + Q * xy) * invd2;
      float yn = sqrt_f(fmaxf(zn2, 1e-12f));
      float proj = (yn > kMaxN) ? (kMaxN * rcp_f(yn)) : 1.f;
      znx *= proj; zny *= proj;
      zn2 *= proj * proj;
      pdn *= proj;
      zx[15 + it] = znx; zy[15 + it] = zny;
      if (l == 0) {
        z2s[w * 20 + 15 + it] = zn2;
        pds[w * 20 + 14 + it] = pdn;
      }
      float n0 = sqrt_f(fmaxf(zn2, 1e-12f));
      float fac = artanh_f(n0) * rcp_f(n0);
      __hip_bfloat162 hv;
      hv.x = __float2bfloat16(fac * znx);
      hv.y = __float2bfloat16(fac * zny);
      *(__hip_bfloat162*)(t0_out + ((size_t)(row0 + w) * 4 + it) * 128 + 2 * l) = hv;
    }
  }
}

// ---------------- K2g (R6-verified) fallback: fused MLP from global t0 ----------------
extern "C" __global__ __launch_bounds__(256, 4)
void mwhf_k2g(const __hip_bfloat16* __restrict__ t0g,
              const __hip_bfloat16* __restrict__ W1bf,
              const __hip_bfloat16* __restrict__ W2bf,
              const float* __restrict__ b1, const float* __restrict__ b2,
              float* __restrict__ outp)
{
  __shared__ __align__(16) __hip_bfloat16 hids[32 * 512];
  s16x8* hidv = (s16x8*)hids;

  const int tid = threadIdx.x;
  const int w = tid >> 6, lane = tid & 63;
  const int l16 = lane & 15, quad = lane >> 4;
  const int mbase = blockIdx.x * 32;
  const int ng = w * 128;

  s16x8 afr[2][4];
#pragma unroll
  for (int s = 0; s < 2; ++s)
#pragma unroll
    for (int kc = 0; kc < 4; ++kc)
      afr[s][kc] = *(const s16x8*)(t0g + (size_t)(mbase + s * 16 + l16) * 128 + kc * 32 + quad * 8);

  f32x4 acc[2][8];
#pragma unroll
  for (int s = 0; s < 2; ++s)
#pragma unroll
    for (int t = 0; t < 8; ++t) acc[s][t] = (f32x4)0.f;

#pragma unroll
  for (int t = 0; t < 8; ++t) {
    const __hip_bfloat16* bp = W1bf + (size_t)(ng + t * 16 + l16) * 128 + quad * 8;
#pragma unroll
    for (int kc = 0; kc < 4; ++kc) {
      s16x8 bfr = *(const s16x8*)(bp + kc * 32);
      acc[0][t] = __builtin_amdgcn_mfma_f32_16x16x32_bf16(afr[0][kc], bfr, acc[0][t], 0, 0, 0);
      acc[1][t] = __builtin_amdgcn_mfma_f32_16x16x32_bf16(afr[1][kc], bfr, acc[1][t], 0, 0, 0);
    }
  }
#pragma unroll
  for (int t = 0; t < 8; ++t) {
    const int nl = ng + t * 16 + l16;
    float bv = b1[nl];
#pragma unroll
    for (int s = 0; s < 2; ++s)
#pragma unroll
      for (int r = 0; r < 4; ++r) {
        int m = s * 16 + quad * 4 + r;
        float h = fmaxf(acc[s][t][r] + bv, 0.f);
        hids[m * 512 + (nl ^ ((m & 7) << 3))] = __float2bfloat16(h);
      }
  }
  __syncthreads();

  {
    const int s2i = w & 1, t2 = w >> 1;
    f32x4 a2 = (f32x4)0.f;
    const int mrow = s2i * 16 + l16;
#pragma unroll 4
    for (int kc = 0; kc < 16; ++kc) {
      s16x8 av = hidv[mrow * 64 + ((kc * 4 + quad) ^ (l16 & 7))];
      s16x8 bfr = *(const s16x8*)(W2bf + (size_t)(t2 * 16 + l16) * 512 + kc * 32 + quad * 8);
      a2 = __builtin_amdgcn_mfma_f32_16x16x32_bf16(av, bfr, a2, 0, 0, 0);
    }
    const int p = t2 * 16 + l16;
    if (p < 24) {
      float bv = b2[p];
#pragma unroll
      for (int r = 0; r < 4; ++r) {
        int m = mbase + s2i * 16 + quad * 4 + r;
        int bbi = m >> 9, it = m & 3, f = (m >> 2) & 127;
        outp[(size_t)bbi * 12288 + (it * 24 + p) * 128 + f] = a2[r] + bv;
      }
    }
  }
}

extern "C" void kernel_launch(void* const* d_in, const int* in_sizes, int n_in,
                              void* d_out, int out_size, void* d_ws, size_t ws_size,
                              hipStream_t stream) {
  (void)in_sizes; (void)n_in; (void)out_size;
  const float* trend = (const float*)d_in[0];
  const float* sc    = (const float*)d_in[1];
  const float* sf    = (const float*)d_in[2];
  const float* rs    = (const float*)d_in[3];
  const float* W_t   = (const float*)d_in[4];
  const float* b_t   = (const float*)d_in[5];
  const float* W_c   = (const float*)d_in[6];
  const float* b_c   = (const float*)d_in[7];
  const float* W_f   = (const float*)d_in[8];
  const float* b_f   = (const float*)d_in[9];
  const float* W_r   = (const float*)d_in[10];
  const float* b_r   = (const float*)d_in[11];
  const float* alpha = (const float*)d_in[12];
  const float* W1    = (const float*)d_in[13];
  const float* b1    = (const float*)d_in[14];
  const float* W2    = (const float*)d_in[15];
  const float* b2    = (const float*)d_in[16];

  char* ws = (char*)d_ws;
  __hip_bfloat16* t0   = (__hip_bfloat16*)(ws + kOffT0);
  __hip_bfloat16* W1bf = (__hip_bfloat16*)(ws + kOffW1);
  __hip_bfloat16* W2bf = (__hip_bfloat16*)(ws + kOffW2);
  __hip_bfloat16* BtH  = (__hip_bfloat16*)(ws + kOffBt);
  __hip_bfloat16* BtM  = BtH + 12288;
  __hip_bfloat16* BtL  = BtM + 12288;
  float* bsum = (float*)(ws + kOffBsum);
  float* z2w  = (float*)(ws + kOffZ2);
  float* zw   = (float*)(ws + kOffZ);
  float* outp = (float*)d_out;

  hipLaunchKernelGGL(mwhf_prep, dim3(73), dim3(256), 0, stream,
                     W1, W2, W_t, W_c, W_f, W_r, b_t, b_c, b_f, b_r,
                     W1bf, W2bf, BtH, BtM, BtL, bsum);
  if (ws_size >= kWsNew) {
    hipLaunchKernelGGL(mwhf_k1a3, dim3(15, 256), dim3(256), 0, stream,
                       trend, sc, sf, rs, BtH, BtM, BtL, bsum, zw, z2w);
    hipLaunchKernelGGL(mwhf_k1bg, dim3(2048), dim3(512), 0, stream,
                       zw, z2w, alpha, W1bf, W2bf, b1, b2, outp);
  } else {
    hipLaunchKernelGGL(mwhf_k1, dim3(4096), dim3(256), 0, stream,
                       trend, sc, sf, rs, BtH, BtM, BtL, bsum, alpha, t0);
    hipLaunchKernelGGL(mwhf_k2g, dim3(2048), dim3(256), 0, stream,
                       t0, W1bf, W2bf, b1, b2, outp);
  }
}

// Round 10
// 344.987 us; speedup vs baseline: 1.0863x; 1.0131x over previous
//
#include <hip/hip_runtime.h>
#include <hip/hip_bf16.h>

namespace {
constexpr int kL = 720, kF = 128;
constexpr int kWin = 15;
constexpr float kEps = 1e-6f;
constexpr float kMaxN = 1.0f - 1e-5f;
constexpr int kT0off = 360;   // (30-15)*24: only last 15 segments matter
constexpr int ZTR = 132;      // zt row stride (floats), +4 pad (fused fallback)
constexpr int AROW = 104;     // A lds row stride bf16 (fused fallback)
constexpr int XR2 = 65;       // k1a4 fp32 X row stride (64 + 1)
constexpr int ZTL = 132;      // k1a4 LDS z-tile row stride (128 + 4)
// ws offsets
constexpr size_t kOffT0   = 0;                    // 16 MiB bf16 t0 (fallback path only)
constexpr size_t kOffW1   = 16777216;             // 128 KiB bf16 W1 [n][k]
constexpr size_t kOffW2   = kOffW1 + 131072;      // 32 KiB bf16 W2 [p][k]
constexpr size_t kOffBt   = kOffW2 + 32768;       // 72 KiB: BtH/BtM/BtL [128][96] bf16
constexpr size_t kOffBsum = kOffBt + 73728;       // 512 B fp32
constexpr size_t kOffZ2   = 17018880;             // 1 MiB fp32 z2 [16384][16]
constexpr size_t kOffZ    = 18874368;             // 126 MiB fp32 z [15 seg][16384 row][128]
constexpr size_t kWsNew   = kOffZ + 125829120;    // 144,703,488 (verified present R5/R7/R8)
}

typedef float f32x4 __attribute__((ext_vector_type(4)));
typedef float f32x2 __attribute__((ext_vector_type(2)));
typedef short s16x8 __attribute__((ext_vector_type(8)));

__device__ __forceinline__ float rcp_f(float x) { return __builtin_amdgcn_rcpf(x); }
__device__ __forceinline__ float sqrt_f(float x) { return __builtin_amdgcn_sqrtf(x); }
__device__ __forceinline__ float tanh_f(float x) {          // x >= 0
  float t = __builtin_amdgcn_exp2f(x * -2.8853900817779268f);
  return (1.0f - t) * rcp_f(1.0f + t);
}
__device__ __forceinline__ float artanh_f(float n) {        // n >= 0
  float nc = fminf(n, 1.0f - 1e-7f);
  return 0.34657359027997264f * __builtin_amdgcn_logf((1.0f + nc) * rcp_f(1.0f - nc));
}

// DPP butterfly add helpers (VALU-latency cross-lane, no LDS pipe).
template<int CTRL>
__device__ __forceinline__ float dpp_add(float v) {
  int mv = __builtin_amdgcn_update_dpp(0, __float_as_int(v), CTRL, 0xF, 0xF, false);
  return v + __int_as_float(mv);
}
__device__ __forceinline__ float sum16(float v) {
  v = dpp_add<0xB1>(v);
  v = dpp_add<0x4E>(v);
  v = dpp_add<0x141>(v);
  v = dpp_add<0x128>(v);
  return v;
}
__device__ __forceinline__ float sum64(float v) {
  v = sum16(v);
  v += __shfl_xor(v, 16);
  v += __shfl_xor(v, 32);
  return v;
}
__device__ __forceinline__ float rlane(float v, int i) {
  return __int_as_float(__builtin_amdgcn_readlane(__float_as_int(v), i));
}
// RNE bf16: returns 16-bit pattern, and the rounded value as f32 via fval.
__device__ __forceinline__ unsigned short rne_bf16(float f, float& fval) {
  unsigned u = __float_as_uint(f);
  unsigned r = (u + 0x7FFFu + ((u >> 16) & 1u)) & 0xFFFF0000u;
  fval = __uint_as_float(r);
  return (unsigned short)(r >> 16);
}

// ---------------- prep: weight repack (bf16 W1/W2 + 3-level split Bt + bsum) ----------------
extern "C" __global__ __launch_bounds__(256)
void mwhf_prep(const float* __restrict__ W1, const float* __restrict__ W2,
               const float* __restrict__ W_t, const float* __restrict__ W_c,
               const float* __restrict__ W_f, const float* __restrict__ W_r,
               const float* __restrict__ b_t, const float* __restrict__ b_c,
               const float* __restrict__ b_f, const float* __restrict__ b_r,
               __hip_bfloat16* __restrict__ W1bf, __hip_bfloat16* __restrict__ W2bf,
               __hip_bfloat16* __restrict__ BtH, __hip_bfloat16* __restrict__ BtM,
               __hip_bfloat16* __restrict__ BtL, float* __restrict__ bsum)
{
  const int b = blockIdx.x, tid = threadIdx.x;
  if (b < 64) {                       // W1 [128k][512n] -> W1bf[n][k]
    const int n0 = b * 8;
    for (int e = tid; e < 1024; e += 256) {
      int n_l = e & 7, k = e >> 3;
      W1bf[(size_t)(n0 + n_l) * 128 + k] = __float2bfloat16(W1[(size_t)k * 512 + n0 + n_l]);
    }
  } else if (b < 68) {                // W2 [512k][24p] -> W2bf[p][k], rows 24..31 zero
    const int k0 = (b - 64) * 128;
    for (int e = tid; e < 4096; e += 256) {
      int p = e >> 7, k_l = e & 127;
      float v = (p < 24) ? W2[(size_t)(k0 + k_l) * 24 + p] : 0.0f;
      W2bf[(size_t)p * 512 + k0 + k_l] = __float2bfloat16(v);
    }
  } else if (b < 72) {                // Bt[d][k=st*24+s] = W_st[s][d], 3-level bf16 split
    const int st = b - 68;
    const float* src = (st == 0) ? W_t : (st == 1) ? W_c : (st == 2) ? W_f : W_r;
    for (int e = tid; e < 3072; e += 256) {
      int s = e >> 7, d = e & 127;
      float x = src[e];                       // src[s*128 + d]
      __hip_bfloat16 h = __float2bfloat16(x);
      float r1 = x - __bfloat162float(h);
      __hip_bfloat16 m = __float2bfloat16(r1);
      float r2 = r1 - __bfloat162float(m);
      const int o = d * 96 + st * 24 + s;
      BtH[o] = h;
      BtM[o] = m;
      BtL[o] = __float2bfloat16(r2);
    }
  } else {
    if (tid < 128) bsum[tid] = b_t[tid] + b_c[tid] + b_f[tid] + b_r[tid];
  }
}

// ---------------- K1a4: coalesced staging + GEMM + expmap0 -> z (STREAMING store) ----
// Block = (seg, bh): M=64 features, K=96, N=128. z layout [seg][16384][128]:
// block output = contiguous 32 KB, written via LDS transpose + nontemporal f32x4 stream.
extern "C" __global__ __launch_bounds__(256, 4)
void mwhf_k1a4(const float* __restrict__ trend,
               const float* __restrict__ seas_c,
               const float* __restrict__ seas_f,
               const float* __restrict__ resid,
               const __hip_bfloat16* __restrict__ BtH,
               const __hip_bfloat16* __restrict__ BtM,
               const __hip_bfloat16* __restrict__ BtL,
               const float* __restrict__ bsum,
               float* __restrict__ z_ws, float* __restrict__ z2_ws)
{
  __shared__ __align__(16) char smemu[64 * ZTL * 4];   // 33792 B union: X (24960 B) / ztile
  float* X = (float*)smemu;          // [96][65] during staging+GEMM
  float* ztile = (float*)smemu;      // [64][132] after barrier

  const int tid = threadIdx.x;
  const int seg = blockIdx.x;        // 0..14
  const int bh  = blockIdx.y;        // 0..255
  const int bb  = bh >> 1;
  const int fh  = (bh & 1) * 64;

  // ---- stage: 96 rows x 256B contiguous, coalesced ----
  {
    const float* ptrs[4] = {trend, seas_c, seas_f, resid};
#pragma unroll
    for (int it = 0; it < 6; ++it) {
      int e = it * 256 + tid;          // 0..1535
      int row = e >> 4;                // 0..95  (k index)
      int fq = (e & 15) * 4;
      int st = row / 24, sI = row - st * 24;
      float4 v = *(const float4*)&ptrs[st][(size_t)(bb * kL + kT0off + seg * 24 + sI) * kF + fh + fq];
      float* dst = &X[row * XR2 + fq];
      dst[0] = v.x; dst[1] = v.y; dst[2] = v.z; dst[3] = v.w;
    }
  }
  __syncthreads();

  const int w = tid >> 6, lane = tid & 63;
  const int l16 = lane & 15, quad = lane >> 4;

  f32x4 acc[8];
#pragma unroll
  for (int t = 0; t < 8; ++t) acc[t] = (f32x4)0.f;

  const __hip_bfloat16* bhp = BtH + l16 * 96 + quad * 8;
  const __hip_bfloat16* bmp = BtM + l16 * 96 + quad * 8;
  const __hip_bfloat16* blp = BtL + l16 * 96 + quad * 8;

#pragma unroll
  for (int ks = 0; ks < 3; ++ks) {
    s16x8 ah, am, al;
    {
      const float* ar = &X[(ks * 32 + quad * 8) * XR2 + w * 16 + l16];
#pragma unroll
      for (int j = 0; j < 8; ++j) {
        float x = ar[j * XR2];
        unsigned hu = __float_as_uint(x) & 0xFFFF0000u;
        float r1 = x - __uint_as_float(hu);
        float mf; unsigned short mb = rne_bf16(r1, mf);
        float r2 = r1 - mf;
        float lf; unsigned short lb = rne_bf16(r2, lf);
        (void)lf;
        ah[j] = (short)(hu >> 16);
        am[j] = (short)mb;
        al[j] = (short)lb;
      }
    }
#pragma unroll
    for (int t = 0; t < 8; ++t) {
      s16x8 bhv = *(const s16x8*)(bhp + t * 1536 + ks * 32);
      s16x8 bmv = *(const s16x8*)(bmp + t * 1536 + ks * 32);
      s16x8 blv = *(const s16x8*)(blp + t * 1536 + ks * 32);
      acc[t] = __builtin_amdgcn_mfma_f32_16x16x32_bf16(ah, bhv, acc[t], 0, 0, 0);
      acc[t] = __builtin_amdgcn_mfma_f32_16x16x32_bf16(am, bhv, acc[t], 0, 0, 0);
      acc[t] = __builtin_amdgcn_mfma_f32_16x16x32_bf16(ah, bmv, acc[t], 0, 0, 0);
      acc[t] = __builtin_amdgcn_mfma_f32_16x16x32_bf16(al, bhv, acc[t], 0, 0, 0);
      acc[t] = __builtin_amdgcn_mfma_f32_16x16x32_bf16(ah, blv, acc[t], 0, 0, 0);
      acc[t] = __builtin_amdgcn_mfma_f32_16x16x32_bf16(am, bmv, acc[t], 0, 0, 0);
    }
  }

  // ---- epilogue: bias, row-norm over d, expmap0 scale ----
  float part[4] = {0.f, 0.f, 0.f, 0.f};
#pragma unroll
  for (int t = 0; t < 8; ++t) {
    float bv = bsum[t * 16 + l16];
#pragma unroll
    for (int r = 0; r < 4; ++r) {
      float v = acc[t][r] + bv;
      acc[t][r] = v;
      part[r] += v * v;
    }
  }
#pragma unroll
  for (int r = 0; r < 4; ++r) part[r] = sum16(part[r]);

  float scl4[4], zz4[4];
#pragma unroll
  for (int r = 0; r < 4; ++r) {
    float v2 = part[r];
    float nv = sqrt_f(fmaxf(v2, 1e-12f));
    float sc = tanh_f(nv) * rcp_f(nv);
    float y2 = sc * sc * v2;
    float yn = sqrt_f(fmaxf(y2, 1e-12f));
    float proj = (yn > kMaxN) ? (kMaxN * rcp_f(yn)) : 1.0f;
    scl4[r] = sc * proj;
    zz4[r] = y2 * proj * proj;
  }
  __syncthreads();   // all X reads complete -> reuse union as ztile

  // transpose through LDS (2-way bank alias only) + z2 scalar writes
#pragma unroll
  for (int r = 0; r < 4; ++r) {
    const int lr = w * 16 + quad * 4 + r;         // local row 0..63
#pragma unroll
    for (int t = 0; t < 8; ++t)
      ztile[lr * ZTL + t * 16 + l16] = acc[t][r] * scl4[r];
    if (l16 == 0) z2_ws[(bh * 64 + lr) * 16 + seg] = zz4[r];
  }
  __syncthreads();

  // streaming contiguous nontemporal store: 32 KB sequential
  {
    float* dst = z_ws + ((size_t)seg * 16384 + (size_t)bh * 64) * 128;
    for (int e = tid; e < 2048; e += 256) {
      int row = e >> 5, d4 = (e & 31) * 4;
      f32x4 v = *(const f32x4*)&ztile[row * ZTL + d4];
      __builtin_nontemporal_store(v, (f32x4*)(dst + (size_t)e * 4));
    }
  }
}

// ---------------- K1bg: fused recurrence + MLP (t0 via LDS, no global t0) ----
// 512 thr = 8 waves. Phase R: wave w = R5-verified recurrence for row ro=blk*8+w,
// t0 -> swizzled LDS tile. Phase 1/2: R6-verified k2g bodies (8-wave / 4-wave).
// z read layout [seg][16384][128], nontemporal.
extern "C" __global__ __launch_bounds__(512, 4)
void mwhf_k1bg(const float* __restrict__ z_ws, const float* __restrict__ z2_ws,
               const float* __restrict__ alpha,
               const __hip_bfloat16* __restrict__ W1bf,
               const __hip_bfloat16* __restrict__ W2bf,
               const float* __restrict__ b1, const float* __restrict__ b2,
               float* __restrict__ outp)
{
  __shared__ __align__(16) __hip_bfloat16 t0s[32 * 128];   // 8 KiB, XOR-swizzled
  __shared__ __align__(16) __hip_bfloat16 hids[32 * 512];  // 32 KiB, XOR-swizzled
  __shared__ float z2s[160];
  __shared__ float pds[160];
  s16x8* hidv = (s16x8*)hids;

  const int tid = threadIdx.x;
  const int w = tid >> 6, l = tid & 63;
  const int l16 = l & 15, quad = l >> 4;
  const int mbase = blockIdx.x * 32;

  // ---- phase R: recurrence (verbatim R5 k1b body, 8 waves, 1 row each) ----
  {
    const int ro = blockIdx.x * 8 + w;
    float zx[19], zy[19];
    const float* zb = z_ws + (size_t)ro * 128 + 2 * l;
#pragma unroll
    for (int j = 0; j < 15; ++j) {
      f32x2 v = __builtin_nontemporal_load((const f32x2*)(zb + (size_t)j * 16384 * 128));
      zx[j] = v.x; zy[j] = v.y;
    }
    if (l < 15) z2s[w * 20 + l] = z2_ws[ro * 16 + l];

    {
      float pd[14];
#pragma unroll
      for (int j = 0; j < 14; ++j) pd[j] = zx[j] * zx[j + 1] + zy[j] * zy[j + 1];
#pragma unroll
      for (int j = 0; j < 14; ++j) pd[j] = sum64(pd[j]);
      if (l == 0) {
#pragma unroll
        for (int j = 0; j < 14; ++j) pds[w * 20 + j] = pd[j];
      }
    }

    const float alp = alpha[0];
    const float cw14 = (l < 14)
        ? __builtin_amdgcn_exp2f((float)(13 - l) * -0.15200309344504997f) * 0.12966260f
        : 0.f;

#pragma unroll
    for (int it = 0; it < 4; ++it) {
      float cA = 0.f, cB = 0.f, cW = 0.f;
      if (l < 14) {
        float dp = pds[w * 20 + it + l];
        float x2 = z2s[w * 20 + it + l];
        float y2 = z2s[w * 20 + it + l + 1];
        cA = 1.f - 2.f * dp + y2;
        cB = 1.f - x2;
        float den = fmaxf(1.f - 2.f * dp + x2 * y2, kEps);
        float invd = rcp_f(den);
        float d2 = (cA * cA * x2 - 2.f * cA * cB * dp + cB * cB * y2) * (invd * invd);
        float n = sqrt_f(fmaxf(d2, 1e-12f));
        float coef = fmaxf(cB, kEps) * artanh_f(n) * rcp_f(n);
        cW = cw14 * coef * invd;
      }
      float avx = 0.f, avy = 0.f;
#pragma unroll
      for (int i = 0; i < 14; ++i) {
        float sA = rlane(cA, i), sB = rlane(cB, i), sW = rlane(cW, i);
        float tx = sB * zx[it + i + 1] - sA * zx[it + i];
        float ty = sB * zy[it + i + 1] - sA * zy[it + i];
        avx += sW * tx;
        avy += sW * ty;
      }
      float vx = alp * avx, vy = alp * avy;
      const int pl = it + 14;
      float x2l = z2s[w * 20 + pl];
      float v2 = vx * vx + vy * vy;
      float xdv = zx[pl] * vx + zy[pl] * vy;
      v2 = sum64(v2);
      xdv = sum64(xdv);
      float nv = sqrt_f(fmaxf(v2, 1e-12f));
      float lam = 2.f * rcp_f(fmaxf(1.f - x2l, kEps));
      float co = tanh_f(0.5f * lam * nv) * rcp_f(nv);
      float s2 = co * co * v2;
      float xy = co * xdv;
      float P = 1.f + 2.f * xy + s2;
      float Q = 1.f - x2l;
      float den2 = fmaxf(1.f + 2.f * xy + x2l * s2, kEps);
      float invd2 = rcp_f(den2);
      float znx = (P * zx[pl] + Q * co * vx) * invd2;
      float zny = (P * zy[pl] + Q * co * vy) * invd2;
      float zn2 = (P * P * x2l + 2.f * P * Q * xy + Q * Q * s2) * (invd2 * invd2);
      float pdn = (P * x2l + Q * xy) * invd2;
      float yn = sqrt_f(fmaxf(zn2, 1e-12f));
      float proj = (yn > kMaxN) ? (kMaxN * rcp_f(yn)) : 1.f;
      znx *= proj; zny *= proj;
      zn2 *= proj * proj;
      pdn *= proj;
      zx[15 + it] = znx; zy[15 + it] = zny;
      if (l == 0) {
        z2s[w * 20 + 15 + it] = zn2;
        pds[w * 20 + 14 + it] = pdn;
      }
      float n0 = sqrt_f(fmaxf(zn2, 1e-12f));
      float fac = artanh_f(n0) * rcp_f(n0);
      __hip_bfloat162 hv;
      hv.x = __float2bfloat16(fac * znx);
      hv.y = __float2bfloat16(fac * zny);
      const int mloc = w * 4 + it;                       // local m 0..31
      const int cs = (2 * l) ^ ((mloc & 7) << 3);        // swizzled halfword col
      *(__hip_bfloat162*)&t0s[mloc * 128 + cs] = hv;
    }
  }
  __syncthreads();

  // ---- phase 1: hid = relu(t0 @ W1 + b1) -> LDS; wave w handles n in [w*64, w*64+64) ----
  {
    const int ng = w * 64;
    s16x8 afr[2][4];
#pragma unroll
    for (int s = 0; s < 2; ++s)
#pragma unroll
      for (int kc = 0; kc < 4; ++kc)
        afr[s][kc] = *(const s16x8*)&t0s[(s * 16 + l16) * 128 +
                                         ((kc * 32 + quad * 8) ^ ((l16 & 7) << 3))];

    f32x4 acc2[2][4];
#pragma unroll
    for (int s = 0; s < 2; ++s)
#pragma unroll
      for (int t = 0; t < 4; ++t) acc2[s][t] = (f32x4)0.f;

#pragma unroll
    for (int t = 0; t < 4; ++t) {
      const __hip_bfloat16* bp = W1bf + (size_t)(ng + t * 16 + l16) * 128 + quad * 8;
#pragma unroll
      for (int kc = 0; kc < 4; ++kc) {
        s16x8 bfr = *(const s16x8*)(bp + kc * 32);
        acc2[0][t] = __builtin_amdgcn_mfma_f32_16x16x32_bf16(afr[0][kc], bfr, acc2[0][t], 0, 0, 0);
        acc2[1][t] = __builtin_amdgcn_mfma_f32_16x16x32_bf16(afr[1][kc], bfr, acc2[1][t], 0, 0, 0);
      }
    }
#pragma unroll
    for (int t = 0; t < 4; ++t) {
      const int nl = ng + t * 16 + l16;
      float bv = b1[nl];
#pragma unroll
      for (int s = 0; s < 2; ++s)
#pragma unroll
        for (int r = 0; r < 4; ++r) {
          int m = s * 16 + quad * 4 + r;
          float h = fmaxf(acc2[s][t][r] + bv, 0.f);
          hids[m * 512 + (nl ^ ((m & 7) << 3))] = __float2bfloat16(h);
        }
    }
  }
  __syncthreads();

  // ---- phase 2: out = hid @ W2 + b2 (waves 0..3, verbatim k2g) ----
  if (w < 4) {
    const int s2i = w & 1, t2 = w >> 1;
    f32x4 a2 = (f32x4)0.f;
    const int mrow = s2i * 16 + l16;
#pragma unroll 4
    for (int kc = 0; kc < 16; ++kc) {
      s16x8 av = hidv[mrow * 64 + ((kc * 4 + quad) ^ (l16 & 7))];
      s16x8 bfr = *(const s16x8*)(W2bf + (size_t)(t2 * 16 + l16) * 512 + kc * 32 + quad * 8);
      a2 = __builtin_amdgcn_mfma_f32_16x16x32_bf16(av, bfr, a2, 0, 0, 0);
    }
    const int p = t2 * 16 + l16;
    if (p < 24) {
      float bv = b2[p];
#pragma unroll
      for (int r = 0; r < 4; ++r) {
        int m = mbase + s2i * 16 + quad * 4 + r;
        int bbi = m >> 9, it = m & 3, f = (m >> 2) & 127;
        outp[(size_t)bbi * 12288 + (it * 24 + p) * 128 + f] = a2[r] + bv;
      }
    }
  }
}

// ---------------- fused K1 (R4/R6-verified) fallback if ws too small for z ----------------
extern "C" __global__ __launch_bounds__(256, 4)
void mwhf_k1(const float* __restrict__ trend,
             const float* __restrict__ seas_c,
             const float* __restrict__ seas_f,
             const float* __restrict__ resid,
             const __hip_bfloat16* __restrict__ BtH,
             const __hip_bfloat16* __restrict__ BtM,
             const __hip_bfloat16* __restrict__ BtL,
             const float* __restrict__ bsum,
             const float* __restrict__ alpha,
             __hip_bfloat16* __restrict__ t0_out)
{
  __shared__ __align__(16) char smem_raw[3 * 64 * AROW * 2];
  __shared__ float z2s[80];
  __shared__ float pds[80];

  float* ublk = (float*)smem_raw;
  __hip_bfloat16* Ah = (__hip_bfloat16*)smem_raw;
  __hip_bfloat16* Am = Ah + 64 * AROW;
  __hip_bfloat16* Al = Am + 64 * AROW;

  const int tid = threadIdx.x;
  const int bix = blockIdx.x;
  const int bb = (bix & 7) * 16 + (bix >> 8);
  const int f0 = ((bix >> 3) & 31) * 4;
  const int row0 = bb * 128 + f0;

  for (int e = tid; e < 192; e += 256) {
    int rr = e / 48, cc = e - rr * 48;
    int off = (rr * 16 + 15) * AROW;
    ((unsigned int*)(Ah + off))[cc] = 0u;
    ((unsigned int*)(Am + off))[cc] = 0u;
    ((unsigned int*)(Al + off))[cc] = 0u;
  }
  {
    const float* ptrs[4] = {trend, seas_c, seas_f, resid};
    for (int e = tid; e < 1440; e += 256) {
      int seg = e / 96;
      int k = e - seg * 96;
      int st = k / 24, s = k - st * 24;
      const float* p = ptrs[st];
      float4 v = *(const float4*)&p[(size_t)(bb * kL + kT0off + seg * 24 + s) * kF + f0];
      float xv[4] = {v.x, v.y, v.z, v.w};
#pragma unroll
      for (int f = 0; f < 4; ++f) {
        int m = f * 16 + seg;
        __hip_bfloat16 h = __float2bfloat16(xv[f]);
        float r1 = xv[f] - __bfloat162float(h);
        __hip_bfloat16 mm = __float2bfloat16(r1);
        float r2 = r1 - __bfloat162float(mm);
        Ah[m * AROW + k] = h;
        Am[m * AROW + k] = mm;
        Al[m * AROW + k] = __float2bfloat16(r2);
      }
    }
  }
  __syncthreads();

  const int w = tid >> 6;
  const int lane = tid & 63;
  const int l16 = lane & 15, quad = lane >> 4;

  f32x4 acc0[8];
  float scale4[4], zz4[4];
  {
    s16x8 ah[3], am[3], al[3];
    const int abase = (w * 16 + l16) * AROW + quad * 8;
#pragma unroll
    for (int ks = 0; ks < 3; ++ks) {
      ah[ks] = *(const s16x8*)(Ah + abase + ks * 32);
      am[ks] = *(const s16x8*)(Am + abase + ks * 32);
      al[ks] = *(const s16x8*)(Al + abase + ks * 32);
    }
#pragma unroll
    for (int t = 0; t < 8; ++t) acc0[t] = (f32x4)0.f;
    const __hip_bfloat16* bhp = BtH + l16 * 96 + quad * 8;
    const __hip_bfloat16* bmp = BtM + l16 * 96 + quad * 8;
    const __hip_bfloat16* blp = BtL + l16 * 96 + quad * 8;
#pragma unroll
    for (int t = 0; t < 8; ++t) {
#pragma unroll
      for (int ks = 0; ks < 3; ++ks) {
        s16x8 bh = *(const s16x8*)(bhp + t * 1536 + ks * 32);
        s16x8 bm = *(const s16x8*)(bmp + t * 1536 + ks * 32);
        s16x8 bl = *(const s16x8*)(blp + t * 1536 + ks * 32);
        acc0[t] = __builtin_amdgcn_mfma_f32_16x16x32_bf16(ah[ks], bh, acc0[t], 0, 0, 0);
        acc0[t] = __builtin_amdgcn_mfma_f32_16x16x32_bf16(am[ks], bh, acc0[t], 0, 0, 0);
        acc0[t] = __builtin_amdgcn_mfma_f32_16x16x32_bf16(ah[ks], bm, acc0[t], 0, 0, 0);
        acc0[t] = __builtin_amdgcn_mfma_f32_16x16x32_bf16(al[ks], bh, acc0[t], 0, 0, 0);
        acc0[t] = __builtin_amdgcn_mfma_f32_16x16x32_bf16(ah[ks], bl, acc0[t], 0, 0, 0);
        acc0[t] = __builtin_amdgcn_mfma_f32_16x16x32_bf16(am[ks], bm, acc0[t], 0, 0, 0);
      }
    }
    float part[4] = {0.f, 0.f, 0.f, 0.f};
#pragma unroll
    for (int t = 0; t < 8; ++t) {
      float bv = bsum[t * 16 + l16];
#pragma unroll
      for (int r = 0; r < 4; ++r) {
        float v = acc0[t][r] + bv;
        acc0[t][r] = v;
        part[r] += v * v;
      }
    }
#pragma unroll
    for (int r = 0; r < 4; ++r) part[r] = sum16(part[r]);
#pragma unroll
    for (int r = 0; r < 4; ++r) {
      float v2 = part[r];
      float nv = sqrt_f(fmaxf(v2, 1e-12f));
      float sc = tanh_f(nv) * rcp_f(nv);
      float y2 = sc * sc * v2;
      float yn = sqrt_f(fmaxf(y2, 1e-12f));
      float proj = (yn > kMaxN) ? (kMaxN * rcp_f(yn)) : 1.0f;
      scale4[r] = sc * proj;
      zz4[r] = y2 * proj * proj;
    }
  }
  __syncthreads();
  {
#pragma unroll
    for (int r = 0; r < 4; ++r) {
      int row = quad * 4 + r;
      if (row < kWin) {
#pragma unroll
        for (int t = 0; t < 8; ++t)
          ublk[(w * kWin + row) * ZTR + t * 16 + l16] = acc0[t][r] * scale4[r];
        if (l16 == 0) z2s[w * 20 + row] = zz4[r];
      }
    }
  }
  __syncthreads();

  {
    const int l = lane;
    float zx[19], zy[19];
#pragma unroll
    for (int j = 0; j < 15; ++j) {
      float2 v = *(const float2*)&ublk[(w * kWin + j) * ZTR + 2 * l];
      zx[j] = v.x; zy[j] = v.y;
    }
    {
      float pd[14];
#pragma unroll
      for (int j = 0; j < 14; ++j) pd[j] = zx[j] * zx[j + 1] + zy[j] * zy[j + 1];
#pragma unroll
      for (int j = 0; j < 14; ++j) pd[j] = sum64(pd[j]);
      if (l == 0) {
#pragma unroll
        for (int j = 0; j < 14; ++j) pds[w * 20 + j] = pd[j];
      }
    }
    const float alp = alpha[0];
    const float cw14 = (l < 14)
        ? __builtin_amdgcn_exp2f((float)(13 - l) * -0.15200309344504997f) * 0.12966260f
        : 0.f;
#pragma unroll
    for (int it = 0; it < 4; ++it) {
      float cA = 0.f, cB = 0.f, cW = 0.f;
      if (l < 14) {
        float dp = pds[w * 20 + it + l];
        float x2 = z2s[w * 20 + it + l];
        float y2 = z2s[w * 20 + it + l + 1];
        cA = 1.f - 2.f * dp + y2;
        cB = 1.f - x2;
        float den = fmaxf(1.f - 2.f * dp + x2 * y2, kEps);
        float invd = rcp_f(den);
        float d2 = (cA * cA * x2 - 2.f * cA * cB * dp + cB * cB * y2) * (invd * invd);
        float n = sqrt_f(fmaxf(d2, 1e-12f));
        float coef = fmaxf(cB, kEps) * artanh_f(n) * rcp_f(n);
        cW = cw14 * coef * invd;
      }
      float avx = 0.f, avy = 0.f;
#pragma unroll
      for (int i = 0; i < 14; ++i) {
        float sA = rlane(cA, i), sB = rlane(cB, i), sW = rlane(cW, i);
        float tx = sB * zx[it + i + 1] - sA * zx[it + i];
        float ty = sB * zy[it + i + 1] - sA * zy[it + i];
        avx += sW * tx;
        avy += sW * ty;
      }
      float vx = alp * avx, vy = alp * avy;
      const int pl = it + 14;
      float x2l = z2s[w * 20 + pl];
      float v2 = vx * vx + vy * vy;
      float xdv = zx[pl] * vx + zy[pl] * vy;
      v2 = sum64(v2);
      xdv = sum64(xdv);
      float nv = sqrt_f(fmaxf(v2, 1e-12f));
      float lam = 2.f * rcp_f(fmaxf(1.f - x2l, kEps));
      float co = tanh_f(0.5f * lam * nv) * rcp_f(nv);
      float s2 = co * co * v2;
      float xy = co * xdv;
      float P = 1.f + 2.f * xy + s2;
      float Q = 1.f - x2l;
      float den2 = fmaxf(1.f + 2.f * xy + x2l * s2, kEps);
      float invd2 = rcp_f(den2);
      float znx = (P * zx[pl] + Q * co * vx) * invd2;
      float zny = (P * zy[pl] + Q * co * vy) * invd2;
      float zn2 = (P * P * x2l + 2.f * P * Q * xy + Q * Q * s2) * (invd2 * invd2);
      float pdn = (P * x2l + Q * xy) * invd2;
      float yn = sqrt_f(fmaxf(zn2, 1e-12f));
      float proj = (yn > kMaxN) ? (kMaxN * rcp_f(yn)) : 1.f;
      znx *= proj; zny *= proj;
      zn2 *= proj * proj;
      pdn *= proj;
      zx[15 + it] = znx; zy[15 + it] = zny;
      if (l == 0) {
        z2s[w * 20 + 15 + it] = zn2;
        pds[w * 20 + 14 + it] = pdn;
      }
      float n0 = sqrt_f(fmaxf(zn2, 1e-12f));
      float fac = artanh_f(n0) * rcp_f(n0);
      __hip_bfloat162 hv;
      hv.x = __float2bfloat16(fac * znx);
      hv.y = __float2bfloat16(fac * zny);
      *(__hip_bfloat162*)(t0_out + ((size_t)(row0 + w) * 4 + it) * 128 + 2 * l) = hv;
    }
  }
}

// ---------------- K2g (R6-verified) fallback: fused MLP from global t0 ----------------
extern "C" __global__ __launch_bounds__(256, 4)
void mwhf_k2g(const __hip_bfloat16* __restrict__ t0g,
              const __hip_bfloat16* __restrict__ W1bf,
              const __hip_bfloat16* __restrict__ W2bf,
              const float* __restrict__ b1, const float* __restrict__ b2,
              float* __restrict__ outp)
{
  __shared__ __align__(16) __hip_bfloat16 hids[32 * 512];
  s16x8* hidv = (s16x8*)hids;

  const int tid = threadIdx.x;
  const int w = tid >> 6, lane = tid & 63;
  const int l16 = lane & 15, quad = lane >> 4;
  const int mbase = blockIdx.x * 32;
  const int ng = w * 128;

  s16x8 afr[2][4];
#pragma unroll
  for (int s = 0; s < 2; ++s)
#pragma unroll
    for (int kc = 0; kc < 4; ++kc)
      afr[s][kc] = *(const s16x8*)(t0g + (size_t)(mbase + s * 16 + l16) * 128 + kc * 32 + quad * 8);

  f32x4 acc[2][8];
#pragma unroll
  for (int s = 0; s < 2; ++s)
#pragma unroll
    for (int t = 0; t < 8; ++t) acc[s][t] = (f32x4)0.f;

#pragma unroll
  for (int t = 0; t < 8; ++t) {
    const __hip_bfloat16* bp = W1bf + (size_t)(ng + t * 16 + l16) * 128 + quad * 8;
#pragma unroll
    for (int kc = 0; kc < 4; ++kc) {
      s16x8 bfr = *(const s16x8*)(bp + kc * 32);
      acc[0][t] = __builtin_amdgcn_mfma_f32_16x16x32_bf16(afr[0][kc], bfr, acc[0][t], 0, 0, 0);
      acc[1][t] = __builtin_amdgcn_mfma_f32_16x16x32_bf16(afr[1][kc], bfr, acc[1][t], 0, 0, 0);
    }
  }
#pragma unroll
  for (int t = 0; t < 8; ++t) {
    const int nl = ng + t * 16 + l16;
    float bv = b1[nl];
#pragma unroll
    for (int s = 0; s < 2; ++s)
#pragma unroll
      for (int r = 0; r < 4; ++r) {
        int m = s * 16 + quad * 4 + r;
        float h = fmaxf(acc[s][t][r] + bv, 0.f);
        hids[m * 512 + (nl ^ ((m & 7) << 3))] = __float2bfloat16(h);
      }
  }
  __syncthreads();

  {
    const int s2i = w & 1, t2 = w >> 1;
    f32x4 a2 = (f32x4)0.f;
    const int mrow = s2i * 16 + l16;
#pragma unroll 4
    for (int kc = 0; kc < 16; ++kc) {
      s16x8 av = hidv[mrow * 64 + ((kc * 4 + quad) ^ (l16 & 7))];
      s16x8 bfr = *(const s16x8*)(W2bf + (size_t)(t2 * 16 + l16) * 512 + kc * 32 + quad * 8);
      a2 = __builtin_amdgcn_mfma_f32_16x16x32_bf16(av, bfr, a2, 0, 0, 0);
    }
    const int p = t2 * 16 + l16;
    if (p < 24) {
      float bv = b2[p];
#pragma unroll
      for (int r = 0; r < 4; ++r) {
        int m = mbase + s2i * 16 + quad * 4 + r;
        int bbi = m >> 9, it = m & 3, f = (m >> 2) & 127;
        outp[(size_t)bbi * 12288 + (it * 24 + p) * 128 + f] = a2[r] + bv;
      }
    }
  }
}

extern "C" void kernel_launch(void* const* d_in, const int* in_sizes, int n_in,
                              void* d_out, int out_size, void* d_ws, size_t ws_size,
                              hipStream_t stream) {
  (void)in_sizes; (void)n_in; (void)out_size;
  const float* trend = (const float*)d_in[0];
  const float* sc    = (const float*)d_in[1];
  const float* sf    = (const float*)d_in[2];
  const float* rs    = (const float*)d_in[3];
  const float* W_t   = (const float*)d_in[4];
  const float* b_t   = (const float*)d_in[5];
  const float* W_c   = (const float*)d_in[6];
  const float* b_c   = (const float*)d_in[7];
  const float* W_f   = (const float*)d_in[8];
  const float* b_f   = (const float*)d_in[9];
  const float* W_r   = (const float*)d_in[10];
  const float* b_r   = (const float*)d_in[11];
  const float* alpha = (const float*)d_in[12];
  const float* W1    = (const float*)d_in[13];
  const float* b1    = (const float*)d_in[14];
  const float* W2    = (const float*)d_in[15];
  const float* b2    = (const float*)d_in[16];

  char* ws = (char*)d_ws;
  __hip_bfloat16* t0   = (__hip_bfloat16*)(ws + kOffT0);
  __hip_bfloat16* W1bf = (__hip_bfloat16*)(ws + kOffW1);
  __hip_bfloat16* W2bf = (__hip_bfloat16*)(ws + kOffW2);
  __hip_bfloat16* BtH  = (__hip_bfloat16*)(ws + kOffBt);
  __hip_bfloat16* BtM  = BtH + 12288;
  __hip_bfloat16* BtL  = BtM + 12288;
  float* bsum = (float*)(ws + kOffBsum);
  float* z2w  = (float*)(ws + kOffZ2);
  float* zw   = (float*)(ws + kOffZ);
  float* outp = (float*)d_out;

  hipLaunchKernelGGL(mwhf_prep, dim3(73), dim3(256), 0, stream,
                     W1, W2, W_t, W_c, W_f, W_r, b_t, b_c, b_f, b_r,
                     W1bf, W2bf, BtH, BtM, BtL, bsum);
  if (ws_size >= kWsNew) {
    hipLaunchKernelGGL(mwhf_k1a4, dim3(15, 256), dim3(256), 0, stream,
                       trend, sc, sf, rs, BtH, BtM, BtL, bsum, zw, z2w);
    hipLaunchKernelGGL(mwhf_k1bg, dim3(2048), dim3(512), 0, stream,
                       zw, z2w, alpha, W1bf, W2bf, b1, b2, outp);
  } else {
    hipLaunchKernelGGL(mwhf_k1, dim3(4096), dim3(256), 0, stream,
                       trend, sc, sf, rs, BtH, BtM, BtL, bsum, alpha, t0);
    hipLaunchKernelGGL(mwhf_k2g, dim3(2048), dim3(256), 0, stream,
                       t0, W1bf, W2bf, b1, b2, outp);
  }
}

// Round 11
// 344.810 us; speedup vs baseline: 1.0869x; 1.0005x over previous
//
#include <hip/hip_runtime.h>
#include <hip/hip_bf16.h>

namespace {
constexpr int kL = 720, kF = 128;
constexpr int kWin = 15;
constexpr float kEps = 1e-6f;
constexpr float kMaxN = 1.0f - 1e-5f;
constexpr int kT0off = 360;   // (30-15)*24: only last 15 segments matter
constexpr int ZTR = 132;      // zt row stride (floats), +4 pad (fused fallback)
constexpr int AROW = 104;     // A lds row stride bf16 (fused fallback)
constexpr int XR2 = 65;       // k1a4 fp32 X row stride (64 + 1)
constexpr int ZTL = 132;      // k1a4 LDS z-tile row stride (128 + 4)
// ws offsets
constexpr size_t kOffT0   = 0;                    // 16 MiB bf16 t0 (fallback path only)
constexpr size_t kOffW1   = 16777216;             // 128 KiB bf16 W1 [n][k]
constexpr size_t kOffW2   = kOffW1 + 131072;      // 32 KiB bf16 W2 [p][k]
constexpr size_t kOffBt   = kOffW2 + 32768;       // 72 KiB: BtH/BtM/BtL [128][96] bf16
constexpr size_t kOffBsum = kOffBt + 73728;       // 512 B fp32
constexpr size_t kOffZ2   = 17018880;             // 1 MiB fp32 z2 [16384][16]
constexpr size_t kOffZ    = 18874368;             // 126 MiB fp32 z [256 bh][15 seg][64][128]
constexpr size_t kWsNew   = kOffZ + 125829120;    // 144,703,488 (verified present R5/R7/R8/R10)
}

typedef float f32x4 __attribute__((ext_vector_type(4)));
typedef short s16x8 __attribute__((ext_vector_type(8)));

__device__ __forceinline__ float rcp_f(float x) { return __builtin_amdgcn_rcpf(x); }
__device__ __forceinline__ float sqrt_f(float x) { return __builtin_amdgcn_sqrtf(x); }
__device__ __forceinline__ float tanh_f(float x) {          // x >= 0
  float t = __builtin_amdgcn_exp2f(x * -2.8853900817779268f);
  return (1.0f - t) * rcp_f(1.0f + t);
}
__device__ __forceinline__ float artanh_f(float n) {        // n >= 0
  float nc = fminf(n, 1.0f - 1e-7f);
  return 0.34657359027997264f * __builtin_amdgcn_logf((1.0f + nc) * rcp_f(1.0f - nc));
}

// DPP butterfly add helpers (VALU-latency cross-lane, no LDS pipe).
template<int CTRL>
__device__ __forceinline__ float dpp_add(float v) {
  int mv = __builtin_amdgcn_update_dpp(0, __float_as_int(v), CTRL, 0xF, 0xF, false);
  return v + __int_as_float(mv);
}
__device__ __forceinline__ float sum16(float v) {
  v = dpp_add<0xB1>(v);
  v = dpp_add<0x4E>(v);
  v = dpp_add<0x141>(v);
  v = dpp_add<0x128>(v);
  return v;
}
__device__ __forceinline__ float sum64(float v) {
  v = sum16(v);
  v += __shfl_xor(v, 16);
  v += __shfl_xor(v, 32);
  return v;
}
__device__ __forceinline__ float rlane(float v, int i) {
  return __int_as_float(__builtin_amdgcn_readlane(__float_as_int(v), i));
}
// RNE bf16: returns 16-bit pattern, and the rounded value as f32 via fval.
__device__ __forceinline__ unsigned short rne_bf16(float f, float& fval) {
  unsigned u = __float_as_uint(f);
  unsigned r = (u + 0x7FFFu + ((u >> 16) & 1u)) & 0xFFFF0000u;
  fval = __uint_as_float(r);
  return (unsigned short)(r >> 16);
}

// ---------------- prep: weight repack (bf16 W1/W2 + 3-level split Bt + bsum) ----------------
extern "C" __global__ __launch_bounds__(256)
void mwhf_prep(const float* __restrict__ W1, const float* __restrict__ W2,
               const float* __restrict__ W_t, const float* __restrict__ W_c,
               const float* __restrict__ W_f, const float* __restrict__ W_r,
               const float* __restrict__ b_t, const float* __restrict__ b_c,
               const float* __restrict__ b_f, const float* __restrict__ b_r,
               __hip_bfloat16* __restrict__ W1bf, __hip_bfloat16* __restrict__ W2bf,
               __hip_bfloat16* __restrict__ BtH, __hip_bfloat16* __restrict__ BtM,
               __hip_bfloat16* __restrict__ BtL, float* __restrict__ bsum)
{
  const int b = blockIdx.x, tid = threadIdx.x;
  if (b < 64) {                       // W1 [128k][512n] -> W1bf[n][k]
    const int n0 = b * 8;
    for (int e = tid; e < 1024; e += 256) {
      int n_l = e & 7, k = e >> 3;
      W1bf[(size_t)(n0 + n_l) * 128 + k] = __float2bfloat16(W1[(size_t)k * 512 + n0 + n_l]);
    }
  } else if (b < 68) {                // W2 [512k][24p] -> W2bf[p][k], rows 24..31 zero
    const int k0 = (b - 64) * 128;
    for (int e = tid; e < 4096; e += 256) {
      int p = e >> 7, k_l = e & 127;
      float v = (p < 24) ? W2[(size_t)(k0 + k_l) * 24 + p] : 0.0f;
      W2bf[(size_t)p * 512 + k0 + k_l] = __float2bfloat16(v);
    }
  } else if (b < 72) {                // Bt[d][k=st*24+s] = W_st[s][d], 3-level bf16 split
    const int st = b - 68;
    const float* src = (st == 0) ? W_t : (st == 1) ? W_c : (st == 2) ? W_f : W_r;
    for (int e = tid; e < 3072; e += 256) {
      int s = e >> 7, d = e & 127;
      float x = src[e];                       // src[s*128 + d]
      __hip_bfloat16 h = __float2bfloat16(x);
      float r1 = x - __bfloat162float(h);
      __hip_bfloat16 m = __float2bfloat16(r1);
      float r2 = r1 - __bfloat162float(m);
      const int o = d * 96 + st * 24 + s;
      BtH[o] = h;
      BtM[o] = m;
      BtL[o] = __float2bfloat16(r2);
    }
  } else {
    if (tid < 128) bsum[tid] = b_t[tid] + b_c[tid] + b_f[tid] + b_r[tid];
  }
}

// ---------------- K1a4: coalesced staging + GEMM + expmap0 -> z (blocked layout) ----
// Flat grid 3840, XCD-chunked swizzle; block -> (seg, bh). M=64 features, K=96, N=128.
// z layout [bh][seg][64][128]: block writes one contiguous 32 KB run (no nt -> L3-resident).
extern "C" __global__ __launch_bounds__(256, 4)
void mwhf_k1a4(const float* __restrict__ trend,
               const float* __restrict__ seas_c,
               const float* __restrict__ seas_f,
               const float* __restrict__ resid,
               const __hip_bfloat16* __restrict__ BtH,
               const __hip_bfloat16* __restrict__ BtM,
               const __hip_bfloat16* __restrict__ BtL,
               const float* __restrict__ bsum,
               float* __restrict__ z_ws, float* __restrict__ z2_ws)
{
  __shared__ __align__(16) char smemu[64 * ZTL * 4];   // 33792 B union: X (24960 B) / ztile
  float* X = (float*)smemu;          // [96][65] during staging+GEMM
  float* ztile = (float*)smemu;      // [64][132] after barrier

  const int tid = threadIdx.x;
  // XCD-chunked bijective swizzle: each XCD gets a contiguous run of (seg,bh) space
  const int bid = blockIdx.x;                 // 0..3839
  const int nb  = (bid & 7) * 480 + (bid >> 3);
  const int seg = nb % 15;                    // 0..14
  const int bh  = nb / 15;                    // 0..255
  const int bb  = bh >> 1;
  const int fh  = (bh & 1) * 64;

  // ---- stage: 96 rows x 256B contiguous, coalesced ----
  {
    const float* ptrs[4] = {trend, seas_c, seas_f, resid};
#pragma unroll
    for (int it = 0; it < 6; ++it) {
      int e = it * 256 + tid;          // 0..1535
      int row = e >> 4;                // 0..95  (k index)
      int fq = (e & 15) * 4;
      int st = row / 24, sI = row - st * 24;
      float4 v = *(const float4*)&ptrs[st][(size_t)(bb * kL + kT0off + seg * 24 + sI) * kF + fh + fq];
      float* dst = &X[row * XR2 + fq];
      dst[0] = v.x; dst[1] = v.y; dst[2] = v.z; dst[3] = v.w;
    }
  }
  __syncthreads();

  const int w = tid >> 6, lane = tid & 63;
  const int l16 = lane & 15, quad = lane >> 4;

  f32x4 acc[8];
#pragma unroll
  for (int t = 0; t < 8; ++t) acc[t] = (f32x4)0.f;

  const __hip_bfloat16* bhp = BtH + l16 * 96 + quad * 8;
  const __hip_bfloat16* bmp = BtM + l16 * 96 + quad * 8;
  const __hip_bfloat16* blp = BtL + l16 * 96 + quad * 8;

#pragma unroll
  for (int ks = 0; ks < 3; ++ks) {
    s16x8 ah, am, al;
    {
      const float* ar = &X[(ks * 32 + quad * 8) * XR2 + w * 16 + l16];
#pragma unroll
      for (int j = 0; j < 8; ++j) {
        float x = ar[j * XR2];
        unsigned hu = __float_as_uint(x) & 0xFFFF0000u;
        float r1 = x - __uint_as_float(hu);
        float mf; unsigned short mb = rne_bf16(r1, mf);
        float r2 = r1 - mf;
        float lf; unsigned short lb = rne_bf16(r2, lf);
        (void)lf;
        ah[j] = (short)(hu >> 16);
        am[j] = (short)mb;
        al[j] = (short)lb;
      }
    }
#pragma unroll
    for (int t = 0; t < 8; ++t) {
      s16x8 bhv = *(const s16x8*)(bhp + t * 1536 + ks * 32);
      s16x8 bmv = *(const s16x8*)(bmp + t * 1536 + ks * 32);
      s16x8 blv = *(const s16x8*)(blp + t * 1536 + ks * 32);
      acc[t] = __builtin_amdgcn_mfma_f32_16x16x32_bf16(ah, bhv, acc[t], 0, 0, 0);
      acc[t] = __builtin_amdgcn_mfma_f32_16x16x32_bf16(am, bhv, acc[t], 0, 0, 0);
      acc[t] = __builtin_amdgcn_mfma_f32_16x16x32_bf16(ah, bmv, acc[t], 0, 0, 0);
      acc[t] = __builtin_amdgcn_mfma_f32_16x16x32_bf16(al, bhv, acc[t], 0, 0, 0);
      acc[t] = __builtin_amdgcn_mfma_f32_16x16x32_bf16(ah, blv, acc[t], 0, 0, 0);
      acc[t] = __builtin_amdgcn_mfma_f32_16x16x32_bf16(am, bmv, acc[t], 0, 0, 0);
    }
  }

  // ---- epilogue: bias, row-norm over d, expmap0 scale ----
  float part[4] = {0.f, 0.f, 0.f, 0.f};
#pragma unroll
  for (int t = 0; t < 8; ++t) {
    float bv = bsum[t * 16 + l16];
#pragma unroll
    for (int r = 0; r < 4; ++r) {
      float v = acc[t][r] + bv;
      acc[t][r] = v;
      part[r] += v * v;
    }
  }
#pragma unroll
  for (int r = 0; r < 4; ++r) part[r] = sum16(part[r]);

  float scl4[4], zz4[4];
#pragma unroll
  for (int r = 0; r < 4; ++r) {
    float v2 = part[r];
    float nv = sqrt_f(fmaxf(v2, 1e-12f));
    float sc = tanh_f(nv) * rcp_f(nv);
    float y2 = sc * sc * v2;
    float yn = sqrt_f(fmaxf(y2, 1e-12f));
    float proj = (yn > kMaxN) ? (kMaxN * rcp_f(yn)) : 1.0f;
    scl4[r] = sc * proj;
    zz4[r] = y2 * proj * proj;
  }
  __syncthreads();   // all X reads complete -> reuse union as ztile

  // transpose through LDS (2-way bank alias only) + z2 scalar writes
#pragma unroll
  for (int r = 0; r < 4; ++r) {
    const int lr = w * 16 + quad * 4 + r;         // local row 0..63
#pragma unroll
    for (int t = 0; t < 8; ++t)
      ztile[lr * ZTL + t * 16 + l16] = acc[t][r] * scl4[r];
    if (l16 == 0) z2_ws[(bh * 64 + lr) * 16 + seg] = zz4[r];
  }
  __syncthreads();

  // contiguous 32 KB sequential store (regular stores -> L3-resident for k1bg read)
  {
    float* dst = z_ws + ((size_t)bh * 15 + seg) * 8192;
    for (int e = tid; e < 2048; e += 256) {
      int row = e >> 5, d4 = (e & 31) * 4;
      f32x4 v = *(const f32x4*)&ztile[row * ZTL + d4];
      *(f32x4*)(dst + (size_t)e * 4) = v;
    }
  }
}

// ---------------- K1bg: fused recurrence + MLP (t0 via LDS, no global t0) ----
// 512 thr = 8 waves. Phase R: wave w = R5-verified recurrence for row ro; z read from
// blocked layout [bh][seg][64][128] -> all of a block's reads within one 491 KB window.
extern "C" __global__ __launch_bounds__(512, 4)
void mwhf_k1bg(const float* __restrict__ z_ws, const float* __restrict__ z2_ws,
               const float* __restrict__ alpha,
               const __hip_bfloat16* __restrict__ W1bf,
               const __hip_bfloat16* __restrict__ W2bf,
               const float* __restrict__ b1, const float* __restrict__ b2,
               float* __restrict__ outp)
{
  __shared__ __align__(16) __hip_bfloat16 t0s[32 * 128];   // 8 KiB, XOR-swizzled
  __shared__ __align__(16) __hip_bfloat16 hids[32 * 512];  // 32 KiB, XOR-swizzled
  __shared__ float z2s[160];
  __shared__ float pds[160];
  s16x8* hidv = (s16x8*)hids;

  const int tid = threadIdx.x;
  const int w = tid >> 6, l = tid & 63;
  const int l16 = l & 15, quad = l >> 4;
  // XCD-chunked bijective swizzle (2048 % 8 == 0)
  const int bid = blockIdx.x;
  const int nb  = (bid & 7) * 256 + (bid >> 3);
  const int mbase = nb * 32;

  // ---- phase R: recurrence (verbatim R5 k1b body, 8 waves, 1 row each) ----
  {
    const int ro = nb * 8 + w;
    const int bh = ro >> 6, lr = ro & 63;
    float zx[19], zy[19];
    const float* zb = z_ws + ((size_t)bh * 15) * 8192 + lr * 128 + 2 * l;
#pragma unroll
    for (int j = 0; j < 15; ++j) {
      float2 v = *(const float2*)(zb + (size_t)j * 8192);
      zx[j] = v.x; zy[j] = v.y;
    }
    if (l < 15) z2s[w * 20 + l] = z2_ws[ro * 16 + l];

    {
      float pd[14];
#pragma unroll
      for (int j = 0; j < 14; ++j) pd[j] = zx[j] * zx[j + 1] + zy[j] * zy[j + 1];
#pragma unroll
      for (int j = 0; j < 14; ++j) pd[j] = sum64(pd[j]);
      if (l == 0) {
#pragma unroll
        for (int j = 0; j < 14; ++j) pds[w * 20 + j] = pd[j];
      }
    }

    const float alp = alpha[0];
    const float cw14 = (l < 14)
        ? __builtin_amdgcn_exp2f((float)(13 - l) * -0.15200309344504997f) * 0.12966260f
        : 0.f;

#pragma unroll
    for (int it = 0; it < 4; ++it) {
      float cA = 0.f, cB = 0.f, cW = 0.f;
      if (l < 14) {
        float dp = pds[w * 20 + it + l];
        float x2 = z2s[w * 20 + it + l];
        float y2 = z2s[w * 20 + it + l + 1];
        cA = 1.f - 2.f * dp + y2;
        cB = 1.f - x2;
        float den = fmaxf(1.f - 2.f * dp + x2 * y2, kEps);
        float invd = rcp_f(den);
        float d2 = (cA * cA * x2 - 2.f * cA * cB * dp + cB * cB * y2) * (invd * invd);
        float n = sqrt_f(fmaxf(d2, 1e-12f));
        float coef = fmaxf(cB, kEps) * artanh_f(n) * rcp_f(n);
        cW = cw14 * coef * invd;
      }
      float avx = 0.f, avy = 0.f;
#pragma unroll
      for (int i = 0; i < 14; ++i) {
        float sA = rlane(cA, i), sB = rlane(cB, i), sW = rlane(cW, i);
        float tx = sB * zx[it + i + 1] - sA * zx[it + i];
        float ty = sB * zy[it + i + 1] - sA * zy[it + i];
        avx += sW * tx;
        avy += sW * ty;
      }
      float vx = alp * avx, vy = alp * avy;
      const int pl = it + 14;
      float x2l = z2s[w * 20 + pl];
      float v2 = vx * vx + vy * vy;
      float xdv = zx[pl] * vx + zy[pl] * vy;
      v2 = sum64(v2);
      xdv = sum64(xdv);
      float nv = sqrt_f(fmaxf(v2, 1e-12f));
      float lam = 2.f * rcp_f(fmaxf(1.f - x2l, kEps));
      float co = tanh_f(0.5f * lam * nv) * rcp_f(nv);
      float s2 = co * co * v2;
      float xy = co * xdv;
      float P = 1.f + 2.f * xy + s2;
      float Q = 1.f - x2l;
      float den2 = fmaxf(1.f + 2.f * xy + x2l * s2, kEps);
      float invd2 = rcp_f(den2);
      float znx = (P * zx[pl] + Q * co * vx) * invd2;
      float zny = (P * zy[pl] + Q * co * vy) * invd2;
      float zn2 = (P * P * x2l + 2.f * P * Q * xy + Q * Q * s2) * (invd2 * invd2);
      float pdn = (P * x2l + Q * xy) * invd2;
      float yn = sqrt_f(fmaxf(zn2, 1e-12f));
      float proj = (yn > kMaxN) ? (kMaxN * rcp_f(yn)) : 1.f;
      znx *= proj; zny *= proj;
      zn2 *= proj * proj;
      pdn *= proj;
      zx[15 + it] = znx; zy[15 + it] = zny;
      if (l == 0) {
        z2s[w * 20 + 15 + it] = zn2;
        pds[w * 20 + 14 + it] = pdn;
      }
      float n0 = sqrt_f(fmaxf(zn2, 1e-12f));
      float fac = artanh_f(n0) * rcp_f(n0);
      __hip_bfloat162 hv;
      hv.x = __float2bfloat16(fac * znx);
      hv.y = __float2bfloat16(fac * zny);
      const int mloc = w * 4 + it;                       // local m 0..31
      const int cs = (2 * l) ^ ((mloc & 7) << 3);        // swizzled halfword col
      *(__hip_bfloat162*)&t0s[mloc * 128 + cs] = hv;
    }
  }
  __syncthreads();

  // ---- phase 1: hid = relu(t0 @ W1 + b1) -> LDS; wave w handles n in [w*64, w*64+64) ----
  {
    const int ng = w * 64;
    s16x8 afr[2][4];
#pragma unroll
    for (int s = 0; s < 2; ++s)
#pragma unroll
      for (int kc = 0; kc < 4; ++kc)
        afr[s][kc] = *(const s16x8*)&t0s[(s * 16 + l16) * 128 +
                                         ((kc * 32 + quad * 8) ^ ((l16 & 7) << 3))];

    f32x4 acc2[2][4];
#pragma unroll
    for (int s = 0; s < 2; ++s)
#pragma unroll
      for (int t = 0; t < 4; ++t) acc2[s][t] = (f32x4)0.f;

#pragma unroll
    for (int t = 0; t < 4; ++t) {
      const __hip_bfloat16* bp = W1bf + (size_t)(ng + t * 16 + l16) * 128 + quad * 8;
#pragma unroll
      for (int kc = 0; kc < 4; ++kc) {
        s16x8 bfr = *(const s16x8*)(bp + kc * 32);
        acc2[0][t] = __builtin_amdgcn_mfma_f32_16x16x32_bf16(afr[0][kc], bfr, acc2[0][t], 0, 0, 0);
        acc2[1][t] = __builtin_amdgcn_mfma_f32_16x16x32_bf16(afr[1][kc], bfr, acc2[1][t], 0, 0, 0);
      }
    }
#pragma unroll
    for (int t = 0; t < 4; ++t) {
      const int nl = ng + t * 16 + l16;
      float bv = b1[nl];
#pragma unroll
      for (int s = 0; s < 2; ++s)
#pragma unroll
        for (int r = 0; r < 4; ++r) {
          int m = s * 16 + quad * 4 + r;
          float h = fmaxf(acc2[s][t][r] + bv, 0.f);
          hids[m * 512 + (nl ^ ((m & 7) << 3))] = __float2bfloat16(h);
        }
    }
  }
  __syncthreads();

  // ---- phase 2: out = hid @ W2 + b2 (waves 0..3, verbatim k2g) ----
  if (w < 4) {
    const int s2i = w & 1, t2 = w >> 1;
    f32x4 a2 = (f32x4)0.f;
    const int mrow = s2i * 16 + l16;
#pragma unroll 4
    for (int kc = 0; kc < 16; ++kc) {
      s16x8 av = hidv[mrow * 64 + ((kc * 4 + quad) ^ (l16 & 7))];
      s16x8 bfr = *(const s16x8*)(W2bf + (size_t)(t2 * 16 + l16) * 512 + kc * 32 + quad * 8);
      a2 = __builtin_amdgcn_mfma_f32_16x16x32_bf16(av, bfr, a2, 0, 0, 0);
    }
    const int p = t2 * 16 + l16;
    if (p < 24) {
      float bv = b2[p];
#pragma unroll
      for (int r = 0; r < 4; ++r) {
        int m = mbase + s2i * 16 + quad * 4 + r;
        int bbi = m >> 9, it = m & 3, f = (m >> 2) & 127;
        outp[(size_t)bbi * 12288 + (it * 24 + p) * 128 + f] = a2[r] + bv;
      }
    }
  }
}

// ---------------- fused K1 (R4/R6-verified) fallback if ws too small for z ----------------
extern "C" __global__ __launch_bounds__(256, 4)
void mwhf_k1(const float* __restrict__ trend,
             const float* __restrict__ seas_c,
             const float* __restrict__ seas_f,
             const float* __restrict__ resid,
             const __hip_bfloat16* __restrict__ BtH,
             const __hip_bfloat16* __restrict__ BtM,
             const __hip_bfloat16* __restrict__ BtL,
             const float* __restrict__ bsum,
             const float* __restrict__ alpha,
             __hip_bfloat16* __restrict__ t0_out)
{
  __shared__ __align__(16) char smem_raw[3 * 64 * AROW * 2];
  __shared__ float z2s[80];
  __shared__ float pds[80];

  float* ublk = (float*)smem_raw;
  __hip_bfloat16* Ah = (__hip_bfloat16*)smem_raw;
  __hip_bfloat16* Am = Ah + 64 * AROW;
  __hip_bfloat16* Al = Am + 64 * AROW;

  const int tid = threadIdx.x;
  const int bix = blockIdx.x;
  const int bb = (bix & 7) * 16 + (bix >> 8);
  const int f0 = ((bix >> 3) & 31) * 4;
  const int row0 = bb * 128 + f0;

  for (int e = tid; e < 192; e += 256) {
    int rr = e / 48, cc = e - rr * 48;
    int off = (rr * 16 + 15) * AROW;
    ((unsigned int*)(Ah + off))[cc] = 0u;
    ((unsigned int*)(Am + off))[cc] = 0u;
    ((unsigned int*)(Al + off))[cc] = 0u;
  }
  {
    const float* ptrs[4] = {trend, seas_c, seas_f, resid};
    for (int e = tid; e < 1440; e += 256) {
      int seg = e / 96;
      int k = e - seg * 96;
      int st = k / 24, s = k - st * 24;
      const float* p = ptrs[st];
      float4 v = *(const float4*)&p[(size_t)(bb * kL + kT0off + seg * 24 + s) * kF + f0];
      float xv[4] = {v.x, v.y, v.z, v.w};
#pragma unroll
      for (int f = 0; f < 4; ++f) {
        int m = f * 16 + seg;
        __hip_bfloat16 h = __float2bfloat16(xv[f]);
        float r1 = xv[f] - __bfloat162float(h);
        __hip_bfloat16 mm = __float2bfloat16(r1);
        float r2 = r1 - __bfloat162float(mm);
        Ah[m * AROW + k] = h;
        Am[m * AROW + k] = mm;
        Al[m * AROW + k] = __float2bfloat16(r2);
      }
    }
  }
  __syncthreads();

  const int w = tid >> 6;
  const int lane = tid & 63;
  const int l16 = lane & 15, quad = lane >> 4;

  f32x4 acc0[8];
  float scale4[4], zz4[4];
  {
    s16x8 ah[3], am[3], al[3];
    const int abase = (w * 16 + l16) * AROW + quad * 8;
#pragma unroll
    for (int ks = 0; ks < 3; ++ks) {
      ah[ks] = *(const s16x8*)(Ah + abase + ks * 32);
      am[ks] = *(const s16x8*)(Am + abase + ks * 32);
      al[ks] = *(const s16x8*)(Al + abase + ks * 32);
    }
#pragma unroll
    for (int t = 0; t < 8; ++t) acc0[t] = (f32x4)0.f;
    const __hip_bfloat16* bhp = BtH + l16 * 96 + quad * 8;
    const __hip_bfloat16* bmp = BtM + l16 * 96 + quad * 8;
    const __hip_bfloat16* blp = BtL + l16 * 96 + quad * 8;
#pragma unroll
    for (int t = 0; t < 8; ++t) {
#pragma unroll
      for (int ks = 0; ks < 3; ++ks) {
        s16x8 bh = *(const s16x8*)(bhp + t * 1536 + ks * 32);
        s16x8 bm = *(const s16x8*)(bmp + t * 1536 + ks * 32);
        s16x8 bl = *(const s16x8*)(blp + t * 1536 + ks * 32);
        acc0[t] = __builtin_amdgcn_mfma_f32_16x16x32_bf16(ah[ks], bh, acc0[t], 0, 0, 0);
        acc0[t] = __builtin_amdgcn_mfma_f32_16x16x32_bf16(am[ks], bh, acc0[t], 0, 0, 0);
        acc0[t] = __builtin_amdgcn_mfma_f32_16x16x32_bf16(ah[ks], bm, acc0[t], 0, 0, 0);
        acc0[t] = __builtin_amdgcn_mfma_f32_16x16x32_bf16(al[ks], bh, acc0[t], 0, 0, 0);
        acc0[t] = __builtin_amdgcn_mfma_f32_16x16x32_bf16(ah[ks], bl, acc0[t], 0, 0, 0);
        acc0[t] = __builtin_amdgcn_mfma_f32_16x16x32_bf16(am[ks], bm, acc0[t], 0, 0, 0);
      }
    }
    float part[4] = {0.f, 0.f, 0.f, 0.f};
#pragma unroll
    for (int t = 0; t < 8; ++t) {
      float bv = bsum[t * 16 + l16];
#pragma unroll
      for (int r = 0; r < 4; ++r) {
        float v = acc0[t][r] + bv;
        acc0[t][r] = v;
        part[r] += v * v;
      }
    }
#pragma unroll
    for (int r = 0; r < 4; ++r) part[r] = sum16(part[r]);
#pragma unroll
    for (int r = 0; r < 4; ++r) {
      float v2 = part[r];
      float nv = sqrt_f(fmaxf(v2, 1e-12f));
      float sc = tanh_f(nv) * rcp_f(nv);
      float y2 = sc * sc * v2;
      float yn = sqrt_f(fmaxf(y2, 1e-12f));
      float proj = (yn > kMaxN) ? (kMaxN * rcp_f(yn)) : 1.0f;
      scale4[r] = sc * proj;
      zz4[r] = y2 * proj * proj;
    }
  }
  __syncthreads();
  {
#pragma unroll
    for (int r = 0; r < 4; ++r) {
      int row = quad * 4 + r;
      if (row < kWin) {
#pragma unroll
        for (int t = 0; t < 8; ++t)
          ublk[(w * kWin + row) * ZTR + t * 16 + l16] = acc0[t][r] * scale4[r];
        if (l16 == 0) z2s[w * 20 + row] = zz4[r];
      }
    }
  }
  __syncthreads();

  {
    const int l = lane;
    float zx[19], zy[19];
#pragma unroll
    for (int j = 0; j < 15; ++j) {
      float2 v = *(const float2*)&ublk[(w * kWin + j) * ZTR + 2 * l];
      zx[j] = v.x; zy[j] = v.y;
    }
    {
      float pd[14];
#pragma unroll
      for (int j = 0; j < 14; ++j) pd[j] = zx[j] * zx[j + 1] + zy[j] * zy[j + 1];
#pragma unroll
      for (int j = 0; j < 14; ++j) pd[j] = sum64(pd[j]);
      if (l == 0) {
#pragma unroll
        for (int j = 0; j < 14; ++j) pds[w * 20 + j] = pd[j];
      }
    }
    const float alp = alpha[0];
    const float cw14 = (l < 14)
        ? __builtin_amdgcn_exp2f((float)(13 - l) * -0.15200309344504997f) * 0.12966260f
        : 0.f;
#pragma unroll
    for (int it = 0; it < 4; ++it) {
      float cA = 0.f, cB = 0.f, cW = 0.f;
      if (l < 14) {
        float dp = pds[w * 20 + it + l];
        float x2 = z2s[w * 20 + it + l];
        float y2 = z2s[w * 20 + it + l + 1];
        cA = 1.f - 2.f * dp + y2;
        cB = 1.f - x2;
        float den = fmaxf(1.f - 2.f * dp + x2 * y2, kEps);
        float invd = rcp_f(den);
        float d2 = (cA * cA * x2 - 2.f * cA * cB * dp + cB * cB * y2) * (invd * invd);
        float n = sqrt_f(fmaxf(d2, 1e-12f));
        float coef = fmaxf(cB, kEps) * artanh_f(n) * rcp_f(n);
        cW = cw14 * coef * invd;
      }
      float avx = 0.f, avy = 0.f;
#pragma unroll
      for (int i = 0; i < 14; ++i) {
        float sA = rlane(cA, i), sB = rlane(cB, i), sW = rlane(cW, i);
        float tx = sB * zx[it + i + 1] - sA * zx[it + i];
        float ty = sB * zy[it + i + 1] - sA * zy[it + i];
        avx += sW * tx;
        avy += sW * ty;
      }
      float vx = alp * avx, vy = alp * avy;
      const int pl = it + 14;
      float x2l = z2s[w * 20 + pl];
      float v2 = vx * vx + vy * vy;
      float xdv = zx[pl] * vx + zy[pl] * vy;
      v2 = sum64(v2);
      xdv = sum64(xdv);
      float nv = sqrt_f(fmaxf(v2, 1e-12f));
      float lam = 2.f * rcp_f(fmaxf(1.f - x2l, kEps));
      float co = tanh_f(0.5f * lam * nv) * rcp_f(nv);
      float s2 = co * co * v2;
      float xy = co * xdv;
      float P = 1.f + 2.f * xy + s2;
      float Q = 1.f - x2l;
      float den2 = fmaxf(1.f + 2.f * xy + x2l * s2, kEps);
      float invd2 = rcp_f(den2);
      float znx = (P * zx[pl] + Q * co * vx) * invd2;
      float zny = (P * zy[pl] + Q * co * vy) * invd2;
      float zn2 = (P * P * x2l + 2.f * P * Q * xy + Q * Q * s2) * (invd2 * invd2);
      float pdn = (P * x2l + Q * xy) * invd2;
      float yn = sqrt_f(fmaxf(zn2, 1e-12f));
      float proj = (yn > kMaxN) ? (kMaxN * rcp_f(yn)) : 1.f;
      znx *= proj; zny *= proj;
      zn2 *= proj * proj;
      pdn *= proj;
      zx[15 + it] = znx; zy[15 + it] = zny;
      if (l == 0) {
        z2s[w * 20 + 15 + it] = zn2;
        pds[w * 20 + 14 + it] = pdn;
      }
      float n0 = sqrt_f(fmaxf(zn2, 1e-12f));
      float fac = artanh_f(n0) * rcp_f(n0);
      __hip_bfloat162 hv;
      hv.x = __float2bfloat16(fac * znx);
      hv.y = __float2bfloat16(fac * zny);
      *(__hip_bfloat162*)(t0_out + ((size_t)(row0 + w) * 4 + it) * 128 + 2 * l) = hv;
    }
  }
}

// ---------------- K2g (R6-verified) fallback: fused MLP from global t0 ----------------
extern "C" __global__ __launch_bounds__(256, 4)
void mwhf_k2g(const __hip_bfloat16* __restrict__ t0g,
              const __hip_bfloat16* __restrict__ W1bf,
              const __hip_bfloat16* __restrict__ W2bf,
              const float* __restrict__ b1, const float* __restrict__ b2,
              float* __restrict__ outp)
{
  __shared__ __align__(16) __hip_bfloat16 hids[32 * 512];
  s16x8* hidv = (s16x8*)hids;

  const int tid = threadIdx.x;
  const int w = tid >> 6, lane = tid & 63;
  const int l16 = lane & 15, quad = lane >> 4;
  const int mbase = blockIdx.x * 32;
  const int ng = w * 128;

  s16x8 afr[2][4];
#pragma unroll
  for (int s = 0; s < 2; ++s)
#pragma unroll
    for (int kc = 0; kc < 4; ++kc)
      afr[s][kc] = *(const s16x8*)(t0g + (size_t)(mbase + s * 16 + l16) * 128 + kc * 32 + quad * 8);

  f32x4 acc[2][8];
#pragma unroll
  for (int s = 0; s < 2; ++s)
#pragma unroll
    for (int t = 0; t < 8; ++t) acc[s][t] = (f32x4)0.f;

#pragma unroll
  for (int t = 0; t < 8; ++t) {
    const __hip_bfloat16* bp = W1bf + (size_t)(ng + t * 16 + l16) * 128 + quad * 8;
#pragma unroll
    for (int kc = 0; kc < 4; ++kc) {
      s16x8 bfr = *(const s16x8*)(bp + kc * 32);
      acc[0][t] = __builtin_amdgcn_mfma_f32_16x16x32_bf16(afr[0][kc], bfr, acc[0][t], 0, 0, 0);
      acc[1][t] = __builtin_amdgcn_mfma_f32_16x16x32_bf16(afr[1][kc], bfr, acc[1][t], 0, 0, 0);
    }
  }
#pragma unroll
  for (int t = 0; t < 8; ++t) {
    const int nl = ng + t * 16 + l16;
    float bv = b1[nl];
#pragma unroll
    for (int s = 0; s < 2; ++s)
#pragma unroll
      for (int r = 0; r < 4; ++r) {
        int m = s * 16 + quad * 4 + r;
        float h = fmaxf(acc[s][t][r] + bv, 0.f);
        hids[m * 512 + (nl ^ ((m & 7) << 3))] = __float2bfloat16(h);
      }
  }
  __syncthreads();

  {
    const int s2i = w & 1, t2 = w >> 1;
    f32x4 a2 = (f32x4)0.f;
    const int mrow = s2i * 16 + l16;
#pragma unroll 4
    for (int kc = 0; kc < 16; ++kc) {
      s16x8 av = hidv[mrow * 64 + ((kc * 4 + quad) ^ (l16 & 7))];
      s16x8 bfr = *(const s16x8*)(W2bf + (size_t)(t2 * 16 + l16) * 512 + kc * 32 + quad * 8);
      a2 = __builtin_amdgcn_mfma_f32_16x16x32_bf16(av, bfr, a2, 0, 0, 0);
    }
    const int p = t2 * 16 + l16;
    if (p < 24) {
      float bv = b2[p];
#pragma unroll
      for (int r = 0; r < 4; ++r) {
        int m = mbase + s2i * 16 + quad * 4 + r;
        int bbi = m >> 9, it = m & 3, f = (m >> 2) & 127;
        outp[(size_t)bbi * 12288 + (it * 24 + p) * 128 + f] = a2[r] + bv;
      }
    }
  }
}

extern "C" void kernel_launch(void* const* d_in, const int* in_sizes, int n_in,
                              void* d_out, int out_size, void* d_ws, size_t ws_size,
                              hipStream_t stream) {
  (void)in_sizes; (void)n_in; (void)out_size;
  const float* trend = (const float*)d_in[0];
  const float* sc    = (const float*)d_in[1];
  const float* sf    = (const float*)d_in[2];
  const float* rs    = (const float*)d_in[3];
  const float* W_t   = (const float*)d_in[4];
  const float* b_t   = (const float*)d_in[5];
  const float* W_c   = (const float*)d_in[6];
  const float* b_c   = (const float*)d_in[7];
  const float* W_f   = (const float*)d_in[8];
  const float* b_f   = (const float*)d_in[9];
  const float* W_r   = (const float*)d_in[10];
  const float* b_r   = (const float*)d_in[11];
  const float* alpha = (const float*)d_in[12];
  const float* W1    = (const float*)d_in[13];
  const float* b1    = (const float*)d_in[14];
  const float* W2    = (const float*)d_in[15];
  const float* b2    = (const float*)d_in[16];

  char* ws = (char*)d_ws;
  __hip_bfloat16* t0   = (__hip_bfloat16*)(ws + kOffT0);
  __hip_bfloat16* W1bf = (__hip_bfloat16*)(ws + kOffW1);
  __hip_bfloat16* W2bf = (__hip_bfloat16*)(ws + kOffW2);
  __hip_bfloat16* BtH  = (__hip_bfloat16*)(ws + kOffBt);
  __hip_bfloat16* BtM  = BtH + 12288;
  __hip_bfloat16* BtL  = BtM + 12288;
  float* bsum = (float*)(ws + kOffBsum);
  float* z2w  = (float*)(ws + kOffZ2);
  float* zw   = (float*)(ws + kOffZ);
  float* outp = (float*)d_out;

  hipLaunchKernelGGL(mwhf_prep, dim3(73), dim3(256), 0, stream,
                     W1, W2, W_t, W_c, W_f, W_r, b_t, b_c, b_f, b_r,
                     W1bf, W2bf, BtH, BtM, BtL, bsum);
  if (ws_size >= kWsNew) {
    hipLaunchKernelGGL(mwhf_k1a4, dim3(3840), dim3(256), 0, stream,
                       trend, sc, sf, rs, BtH, BtM, BtL, bsum, zw, z2w);
    hipLaunchKernelGGL(mwhf_k1bg, dim3(2048), dim3(512), 0, stream,
                       zw, z2w, alpha, W1bf, W2bf, b1, b2, outp);
  } else {
    hipLaunchKernelGGL(mwhf_k1, dim3(4096), dim3(256), 0, stream,
                       trend, sc, sf, rs, BtH, BtM, BtL, bsum, alpha, t0);
    hipLaunchKernelGGL(mwhf_k2g, dim3(2048), dim3(256), 0, stream,
                       t0, W1bf, W2bf, b1, b2, outp);
  }
}